// Round 2
// baseline (363.369 us; speedup 1.0000x reference)
//
#include <hip/hip_runtime.h>

// ============================================================================
// RegionNonLocalEnhancedDenseBlock on MI355X (gfx950) — Round 7
//  - attn_kernel REWRITTEN around swapped QK^T (S^T = mfma(K,Q)):
//      * P stays in registers: v_cvt_pk_bf16_f32 in-lane packing + 8 shfl
//        + 4 selects per K-slice replace the 64-scalar-store P LDS
//        round-trip (was ~340 VALU + 2 latency chains per M-tile).
//      * in-register softmax (63 fmax + 2 shfl_xor instead of per-row
//        lane reduction).
//      * vl pad 260->268 u16 (V^T reads were the 1.05M bank conflicts).
//      * 8-wave blocks, grid 512 = exactly 2 blocks/CU (was 1024@3/CU
//        -> 1.33 dispatch rounds).
//      * Wq/Wo repacked to bf16 host-side kernel (Wo loaded at use: -16 VGPR).
//  - kvx (r6 coalesced-LDS version), conv3x3, fuse unchanged.
// ============================================================================

typedef short s16x8 __attribute__((ext_vector_type(8)));
typedef float f32x4 __attribute__((ext_vector_type(4)));
typedef unsigned short ushort_t;

__device__ __forceinline__ unsigned short f2bf(float f) {
  union { float f; unsigned int u; } v; v.f = f;
  unsigned int r = v.u + 0x7fffu + ((v.u >> 16) & 1u);  // RNE
  return (unsigned short)(r >> 16);
}
__device__ __forceinline__ float bf2f(unsigned short h) {
  union { unsigned int u; float f; } v; v.u = ((unsigned int)h) << 16;
  return v.f;
}
// packed f32x2 -> bf16x2 (RNE), lo = a, hi = b
__device__ __forceinline__ unsigned int cvtpk(float a, float b) {
  unsigned int r;
  asm("v_cvt_pk_bf16_f32 %0, %1, %2" : "=v"(r) : "v"(a), "v"(b));
  return r;
}

// ---------------------------------------------------------------------------
// Repack conv/fuse weights -> bf16 MFMA B-frag order; Wq/Wo -> linear bf16.
// ---------------------------------------------------------------------------
__global__ void repack_kernel(const float* __restrict__ W1, const float* __restrict__ W2,
                              const float* __restrict__ W3, const float* __restrict__ Wf,
                              const float* __restrict__ Wq, const float* __restrict__ Wo,
                              ushort_t* __restrict__ wc1, ushort_t* __restrict__ wc2,
                              ushort_t* __restrict__ wc3, ushort_t* __restrict__ wff,
                              ushort_t* __restrict__ woq, ushort_t* __restrict__ wou)
{
  const int i = blockIdx.x * 256 + threadIdx.x;
  if (i < 18432) {  // W1 [32][64][3][3], Kg=8
    int j = i & 7, o = (i >> 3) & 31, r = i >> 8, tap = r >> 3, kg = r & 7;
    wc1[i] = f2bf(W1[o * 576 + (kg * 8 + j) * 9 + tap]);
  }
  if (i < 27648) {  // W2 [32][96][3][3], Kg=12
    int j = i & 7, o = (i >> 3) & 31, r = i >> 8, tap = r / 12, kg = r % 12;
    wc2[i] = f2bf(W2[o * 864 + (kg * 8 + j) * 9 + tap]);
  }
  if (i < 36864) {  // W3 [32][128][3][3], Kg=16
    int j = i & 7, o = (i >> 3) & 31, r = i >> 8, tap = r >> 4, kg = r & 15;
    wc3[i] = f2bf(W3[o * 1152 + (kg * 8 + j) * 9 + tap]);
  }
  if (i < 10240) {  // Wf [64][160], Kg=20
    int j = i & 7, o = (i >> 3) & 63, kg = i >> 9;
    wff[i] = f2bf(Wf[o * 160 + kg * 8 + j]);
  }
  if (i < 2048) {   // Wq [32][64] linear, Wo [64][32] linear
    woq[i] = f2bf(Wq[i]);
    wou[i] = f2bf(Wo[i]);
  }
}

// ---------------------------------------------------------------------------
// kvx_kernel: grid 1024 = n(4) x pooled_row(128) x x_half(2). (unchanged r6)
// ---------------------------------------------------------------------------
__global__ __launch_bounds__(256, 4) void kvx_kernel(
    const float* __restrict__ x,
    const float* __restrict__ Wk, const float* __restrict__ bk,
    const float* __restrict__ Wv, const float* __restrict__ bv,
    ushort_t* __restrict__ xt, ushort_t* __restrict__ kg, ushort_t* __restrict__ vt)
{
  __shared__ __attribute__((aligned(16))) ushort_t lds[64 * 258];  // [c][258]
  __shared__ ushort_t kvs[4][8][64];  // [wave][kpos_local][K 0..31 | V 32..63]

  const int bid = blockIdx.x;
  const int n   = bid >> 8;
  const int rem = bid & 255;
  const int pr  = rem >> 1;            // pooled row 0..127
  const int xh  = rem & 1;             // x half
  const int tid = threadIdx.x, lane = tid & 63, wv = tid >> 6;
  const int quad = lane >> 4, l15 = lane & 15;

  const int y0 = pr * 2;
  const int x0 = xh * 128;
  const int gh = pr >> 4, pyc = pr & 15;

  const float* xblk = x + (size_t)n * (64 * 65536) + (size_t)(y0 * 256 + x0);
  ushort_t*    xtn  = xt + (size_t)n * (65536 * 64);

  // ---- phase 1: x -> LDS (coalesced 512B runs per instruction)
#pragma unroll 4
  for (int i = 0; i < 16; ++i) {
    const int idx = (i << 8) + tid;          // 0..4095 float4s
    const int c  = idx >> 6;                 // 64 float4 per channel
    const int r  = (idx >> 5) & 1;
    const int sg = idx & 31;
    const f32x4 v = *(const f32x4*)(xblk + (size_t)c * 65536 + r * 256 + sg * 4);
    const unsigned int lo = (unsigned int)f2bf(v[0]) | ((unsigned int)f2bf(v[1]) << 16);
    const unsigned int hi = (unsigned int)f2bf(v[2]) | ((unsigned int)f2bf(v[3]) << 16);
    const int base = c * 258 + (r << 7) + (sg << 2);   // u16 index, 4B aligned
    *(unsigned int*)&lds[base]     = lo;
    *(unsigned int*)&lds[base + 2] = hi;
  }

  // ---- K/V weight B-frags (L2-resident, overlaps phase-1 drain)
  s16x8 wkf[2][2], wvf[2][2];
#pragma unroll
  for (int ks = 0; ks < 2; ++ks)
#pragma unroll
    for (int nt = 0; nt < 2; ++nt) {
      const int off = (nt * 16 + l15) * 64 + ks * 32 + quad * 8;
      s16x8 tk, tv;
#pragma unroll
      for (int j = 0; j < 8; ++j) {
        tk[j] = (short)f2bf(Wk[off + j]);
        tv[j] = (short)f2bf(Wv[off + j]);
      }
      wkf[ks][nt] = tk; wvf[ks][nt] = tv;
    }
  float bkv[2], bvv[2];
#pragma unroll
  for (int nt = 0; nt < 2; ++nt) {
    bkv[nt] = bk[nt * 16 + l15];
    bvv[nt] = bv[nt * 16 + l15];
  }

  __syncthreads();

  // ---- phase 2a: xt stores — lane = (pixel_octet, ch_octet); 1KB contiguous
  {
    const int g  = lane & 7;        // channel octet
    const int pa = lane >> 3;       // pixel within octet run
#pragma unroll
    for (int s = 0; s < 8; ++s) {
      const int p = (wv << 6) + (s << 3) + pa;        // 0..255 local pixel
      s16x8 v;
#pragma unroll
      for (int j = 0; j < 8; ++j) v[j] = (short)lds[(g * 8 + j) * 258 + p];
      const int P = (y0 + (p >> 7)) * 256 + x0 + (p & 127);
      *(s16x8*)(xtn + (size_t)P * 64 + g * 8) = v;
    }
  }

  // ---- phase 2b: K/V — 2 x-tiles (16px) per wave, both rows, pool 2x2
  const f32x4 zf = {0.f, 0.f, 0.f, 0.f};
#pragma unroll
  for (int tt = 0; tt < 2; ++tt) {
    const int t   = wv * 2 + tt;          // x-tile 0..7 (local)
    const int px0 = t * 16 + l15;

    s16x8 a[2][2];                        // [row][ks]
#pragma unroll
    for (int r = 0; r < 2; ++r)
#pragma unroll
      for (int ks = 0; ks < 2; ++ks) {
        s16x8 v;
#pragma unroll
        for (int j = 0; j < 8; ++j)
          v[j] = (short)lds[(ks * 32 + quad * 8 + j) * 258 + (r << 7) + px0];
        a[r][ks] = v;
      }

    f32x4 kd[2][2], vd[2][2];             // [row][nt]
#pragma unroll
    for (int r = 0; r < 2; ++r)
#pragma unroll
      for (int nt = 0; nt < 2; ++nt) {
        f32x4 k0 = __builtin_amdgcn_mfma_f32_16x16x32_bf16(a[r][0], wkf[0][nt], zf, 0, 0, 0);
        kd[r][nt] = __builtin_amdgcn_mfma_f32_16x16x32_bf16(a[r][1], wkf[1][nt], k0, 0, 0, 0);
        f32x4 v0 = __builtin_amdgcn_mfma_f32_16x16x32_bf16(a[r][0], wvf[0][nt], zf, 0, 0, 0);
        vd[r][nt] = __builtin_amdgcn_mfma_f32_16x16x32_bf16(a[r][1], wvf[1][nt], v0, 0, 0, 0);
      }

    // pool 2x2 (x-pairs are adjacent D-rows = adjacent regs; y-pairs = r)
#pragma unroll
    for (int nt = 0; nt < 2; ++nt)
#pragma unroll
      for (int rr = 0; rr < 2; ++rr) {
        const float kp = fmaxf(fmaxf(kd[0][nt][2 * rr], kd[0][nt][2 * rr + 1]),
                               fmaxf(kd[1][nt][2 * rr], kd[1][nt][2 * rr + 1])) + bkv[nt];
        const float vp = fmaxf(fmaxf(vd[0][nt][2 * rr], vd[0][nt][2 * rr + 1]),
                               fmaxf(vd[1][nt][2 * rr], vd[1][nt][2 * rr + 1])) + bvv[nt];
        kvs[wv][quad * 2 + rr][nt * 16 + l15]      = f2bf(kp);
        kvs[wv][quad * 2 + rr][32 + nt * 16 + l15] = f2bf(vp);
      }

    const int gw    = xh * 4 + (t >> 1);
    const int cell  = (n << 6) + (gh << 3) + gw;
    const int kposb = pyc * 16 + (t & 1) * 8;
    if (lane < 32) {
      const s16x8 vv = *(const s16x8*)&kvs[wv][lane >> 2][(lane & 3) * 8];
      *(s16x8*)(kg + ((size_t)(cell << 8) + kposb + (lane >> 2)) * 32 + (lane & 3) * 8) = vv;
    } else {
      const int ch = lane - 32;
      s16x8 vv;
#pragma unroll
      for (int r = 0; r < 8; ++r) vv[r] = (short)kvs[wv][r][32 + ch];
      *(s16x8*)(vt + (size_t)(cell << 13) + ch * 256 + kposb) = vv;
    }
  }
}

// ---------------------------------------------------------------------------
// attn_kernel v3: grid 512 (2 blocks/cell), 8 waves, 4 M-tiles/wave.
// Swapped S^T = mfma(K,Q) -> in-lane P pack (cvt_pk) + shfl redistribution.
// ---------------------------------------------------------------------------
__global__ __launch_bounds__(512, 4) void attn_kernel(
    const ushort_t* __restrict__ xt, const ushort_t* __restrict__ kg,
    const ushort_t* __restrict__ vt,
    const ushort_t* __restrict__ woq, const float* __restrict__ bq,
    const ushort_t* __restrict__ wou, const float* __restrict__ bo,
    const float* __restrict__ gamma_p, ushort_t* __restrict__ f0)
{
  __shared__ __attribute__((aligned(16))) ushort_t kl[256 * 36];  // K [kpos][32] pad36
  __shared__ __attribute__((aligned(16))) ushort_t vl[32 * 268];  // V^T [ch][256] pad268
  __shared__ __attribute__((aligned(16))) ushort_t un[8][1152];   // per-wave scratch

  const int bid = blockIdx.x;
  const int cell = bid >> 1;
  const int part = bid & 1;
  const int tid = threadIdx.x, lane = tid & 63, wv = tid >> 6;
  const int quad = lane >> 4, l15 = lane & 15;

  const int n  = cell >> 6;
  const int gh = (cell >> 3) & 7;
  const int gw = cell & 7;
  const int y0 = gh * 32, xc0 = gw * 32;

  const ushort_t* xtn = xt + (size_t)n * (65536 * 64);
  ushort_t*       f0n = f0 + (size_t)n * (65536 * 64);
  const ushort_t* kc  = kg + (size_t)(cell << 8) * 32;
  const ushort_t* vc  = vt + (size_t)(cell << 13);

  // ---- stage K and V^T into LDS (one pass, b128 both sides)
  for (int idx = tid; idx < 1024; idx += 512) {
    const int kpos = idx >> 2, cg = idx & 3;
    *(s16x8*)&kl[kpos * 36 + cg * 8] = *(const s16x8*)(kc + kpos * 32 + cg * 8);
  }
  for (int idx = tid; idx < 1024; idx += 512) {
    const int ch = idx >> 5, seg = idx & 31;
    *(s16x8*)&vl[ch * 268 + seg * 8] = *(const s16x8*)(vc + ch * 256 + seg * 8);
  }

  const float gamma = gamma_p[0];

  // Wq B-frags from repacked bf16 (resident; Wo loaded at use)
  s16x8 wqf[2][2];
#pragma unroll
  for (int ks = 0; ks < 2; ++ks)
#pragma unroll
    for (int nt = 0; nt < 2; ++nt)
      wqf[ks][nt] = *(const s16x8*)(woq + (nt * 16 + l15) * 64 + ks * 32 + quad * 8);
  float bqv[2]; bqv[0] = bq[l15]; bqv[1] = bq[16 + l15];
  float bov[4];
#pragma unroll
  for (int nt = 0; nt < 4; ++nt) bov[nt] = bo[nt * 16 + l15];

  __syncthreads();   // K/V staged

  ushort_t* uw = un[wv];
  const f32x4 zf = {0.f, 0.f, 0.f, 0.f};

  // shuffle geometry for P redistribution (see header comment)
  const int src0 = ((quad & 1) << 5) + l15;   // lane (l15, 2*(quad&1))
  const int src1 = src0 + 16;                 // lane (l15, 2*(quad&1)+1)
  const int hsel = quad >> 1;                 // selects pk[2kk+hsel]

#pragma unroll 1
  for (int it = 0; it < 4; ++it) {
    const int mt = part * 32 + wv * 4 + it;   // 0..63
    const int pbase = mt * 16;

    const int p = pbase + l15;
    const int yy = p >> 5, xx = p & 31;
    const size_t pixg = (size_t)((y0 + yy) * 256 + xc0 + xx);

    // ---- Q-gen from xt
    const s16x8 a0 = *(const s16x8*)(xtn + pixg * 64 + quad * 8);
    const s16x8 a1 = *(const s16x8*)(xtn + pixg * 64 + 32 + quad * 8);
    f32x4 qd0 = zf, qd1 = zf;
    qd0 = __builtin_amdgcn_mfma_f32_16x16x32_bf16(a0, wqf[0][0], qd0, 0, 0, 0);
    qd0 = __builtin_amdgcn_mfma_f32_16x16x32_bf16(a1, wqf[1][0], qd0, 0, 0, 0);
    qd1 = __builtin_amdgcn_mfma_f32_16x16x32_bf16(a0, wqf[0][1], qd1, 0, 0, 0);
    qd1 = __builtin_amdgcn_mfma_f32_16x16x32_bf16(a1, wqf[1][1], qd1, 0, 0, 0);
    // qt phase of union buffer (stride 40)
#pragma unroll
    for (int i = 0; i < 4; ++i) {
      uw[(quad * 4 + i) * 40 + l15]      = f2bf(qd0[i] + bqv[0]);
      uw[(quad * 4 + i) * 40 + 16 + l15] = f2bf(qd1[i] + bqv[1]);
    }
    const s16x8 qa = *(const s16x8*)&uw[l15 * 40 + quad * 8];

    // ---- S^T = K.Q^T (swapped): lane (l15,q) reg i of tile nt holds
    //      S[kpos = 16nt+4q+i][qpix = l15]  -> 4 consecutive kpos in regs
    f32x4 St[16];
#pragma unroll
    for (int nt = 0; nt < 16; ++nt) {
      const s16x8 kb = *(const s16x8*)&kl[(nt * 16 + l15) * 36 + quad * 8];
      St[nt] = __builtin_amdgcn_mfma_f32_16x16x32_bf16(kb, qa, zf, 0, 0, 0);
    }

    // ---- in-register softmax over 256 kpos for qpix=l15
    float m = St[0][0];
#pragma unroll
    for (int nt = 0; nt < 16; ++nt) {
      m = fmaxf(m, fmaxf(fmaxf(St[nt][0], St[nt][1]), fmaxf(St[nt][2], St[nt][3])));
    }
    m = fmaxf(m, __shfl_xor(m, 16, 64));
    m = fmaxf(m, __shfl_xor(m, 32, 64));
    float s = 0.f;
    unsigned int pku[32];   // pk[nt][pr] = pku[2nt+pr]; lo kpos even
#pragma unroll
    for (int nt = 0; nt < 16; ++nt) {
      const float e0 = __expf(St[nt][0] - m);
      const float e1 = __expf(St[nt][1] - m);
      const float e2 = __expf(St[nt][2] - m);
      const float e3 = __expf(St[nt][3] - m);
      s += (e0 + e1) + (e2 + e3);
      pku[2 * nt]     = cvtpk(e0, e1);
      pku[2 * nt + 1] = cvtpk(e2, e3);
    }
    s += __shfl_xor(s, 16, 64);
    s += __shfl_xor(s, 32, 64);

    // ---- O = P.V^T : P A-frags assembled via shfl (no LDS round-trip).
    // target lane (l15,q') word w needs pk[2kk+(q'>>1)][w&1] from lane
    // (l15, 2(q'&1) + (w>>1)).
    f32x4 O0 = zf, O1 = zf;
#pragma unroll
    for (int kk = 0; kk < 8; ++kk) {
      const int A0 = __shfl((int)pku[4 * kk + 0], src0, 64);
      const int B0 = __shfl((int)pku[4 * kk + 2], src0, 64);
      const int A1 = __shfl((int)pku[4 * kk + 1], src0, 64);
      const int B1 = __shfl((int)pku[4 * kk + 3], src0, 64);
      const int A2 = __shfl((int)pku[4 * kk + 0], src1, 64);
      const int B2 = __shfl((int)pku[4 * kk + 2], src1, 64);
      const int A3 = __shfl((int)pku[4 * kk + 1], src1, 64);
      const int B3 = __shfl((int)pku[4 * kk + 3], src1, 64);
      union { int w[4]; s16x8 v; } pa;
      pa.w[0] = hsel ? B0 : A0;
      pa.w[1] = hsel ? B1 : A1;
      pa.w[2] = hsel ? B2 : A2;
      pa.w[3] = hsel ? B3 : A3;
      const int kb0 = kk * 32 + quad * 8;
      const s16x8 vb0 = *(const s16x8*)&vl[l15 * 268 + kb0];
      const s16x8 vb1 = *(const s16x8*)&vl[(16 + l15) * 268 + kb0];
      O0 = __builtin_amdgcn_mfma_f32_16x16x32_bf16(pa.v, vb0, O0, 0, 0, 0);
      O1 = __builtin_amdgcn_mfma_f32_16x16x32_bf16(pa.v, vb1, O1, 0, 0, 0);
    }

    // row sums for this lane's O rows (qpix = 4*quad+i)
    float rv[4];
#pragma unroll
    for (int i = 0; i < 4; ++i) rv[i] = __shfl(s, quad * 4 + i, 64);

    // ---- normalize, C->A (ot phase, stride 40), project Wo
#pragma unroll
    for (int i = 0; i < 4; ++i) {
      const float inv = 1.0f / rv[i];
      uw[(quad * 4 + i) * 40 + l15]      = f2bf(O0[i] * inv);
      uw[(quad * 4 + i) * 40 + 16 + l15] = f2bf(O1[i] * inv);
    }
    const s16x8 oa = *(const s16x8*)&uw[l15 * 40 + quad * 8];
    // ft phase (stride 72): [q][64ch]; Wo B-frags loaded at use (L2-hot)
#pragma unroll
    for (int nt = 0; nt < 4; ++nt) {
      const s16x8 wofn = *(const s16x8*)(wou + (nt * 16 + l15) * 32 + quad * 8);
      f32x4 D = __builtin_amdgcn_mfma_f32_16x16x32_bf16(oa, wofn, zf, 0, 0, 0);
#pragma unroll
      for (int i = 0; i < 4; ++i)
        uw[(quad * 4 + i) * 72 + nt * 16 + l15] = f2bf(gamma * (D[i] + bov[nt]));
    }

    // ---- epilogue: +xt residual, packed cvt, 16B vector stores
    {
      const s16x8 fv0 = *(const s16x8*)&uw[l15 * 72 + quad * 16];
      const s16x8 fv1 = *(const s16x8*)&uw[l15 * 72 + quad * 16 + 8];
      const s16x8 xv0 = *(const s16x8*)(xtn + pixg * 64 + quad * 16);
      const s16x8 xv1 = *(const s16x8*)(xtn + pixg * 64 + quad * 16 + 8);
      union { unsigned int w[4]; s16x8 v; } r0, r1;
#pragma unroll
      for (int k = 0; k < 4; ++k) {
        const float p0 = bf2f((unsigned short)fv0[2 * k])     + bf2f((unsigned short)xv0[2 * k]);
        const float p1 = bf2f((unsigned short)fv0[2 * k + 1]) + bf2f((unsigned short)xv0[2 * k + 1]);
        const float p2 = bf2f((unsigned short)fv1[2 * k])     + bf2f((unsigned short)xv1[2 * k]);
        const float p3 = bf2f((unsigned short)fv1[2 * k + 1]) + bf2f((unsigned short)xv1[2 * k + 1]);
        r0.w[k] = cvtpk(p0, p1);
        r1.w[k] = cvtpk(p2, p3);
      }
      *(s16x8*)(f0n + pixg * 64 + quad * 16)     = r0.v;
      *(s16x8*)(f0n + pixg * 64 + quad * 16 + 8) = r1.v;
    }
  }
}

// ---------------------------------------------------------------------------
// conv3x3 + ReLU via bf16 MFMA implicit GEMM (unchanged).
// ---------------------------------------------------------------------------
template <int NCHUNK>
__global__ __launch_bounds__(256) void conv3_kernel(
    const ushort_t* __restrict__ s0, const ushort_t* __restrict__ s1,
    const ushort_t* __restrict__ s2, const ushort_t* __restrict__ wc,
    const float* __restrict__ bias, ushort_t* __restrict__ outp)
{
  __shared__ __attribute__((aligned(16))) ushort_t tile[612 * 40];

  const int bid = blockIdx.x;
  const int n = bid >> 7;
  const int t = bid & 127;
  const int ty0 = (t >> 3) * 16;
  const int tx0 = (t & 7) * 32;
  const int tid = threadIdx.x, lane = tid & 63, wv = tid >> 6;
  const int quad = lane >> 4, l15 = lane & 15;
  constexpr int Kg = NCHUNK * 4;

  const f32x4 zf = {0.f, 0.f, 0.f, 0.f};
  f32x4 acc[4][2][2];
#pragma unroll
  for (int r = 0; r < 4; ++r)
#pragma unroll
    for (int h = 0; h < 2; ++h) { acc[r][h][0] = zf; acc[r][h][1] = zf; }

  for (int ch = 0; ch < NCHUNK; ++ch) {
    const ushort_t* src; int cstr, cbase;
    if (ch < 2)       { src = s0 + (size_t)n * (65536 * 64); cstr = 64; cbase = ch * 32; }
    else if (ch == 2) { src = s1 + (size_t)n * (65536 * 32); cstr = 32; cbase = 0; }
    else              { src = s2 + (size_t)n * (65536 * 32); cstr = 32; cbase = 0; }

    __syncthreads();
    for (int u = tid; u < 2448; u += 256) {
      const int pix = u >> 2, cg = u & 3;
      const int lr = pix / 34, lc = pix - lr * 34;
      const int gy = ty0 - 1 + lr, gx = tx0 - 1 + lc;
      s16x8 v = {0, 0, 0, 0, 0, 0, 0, 0};
      if ((unsigned)gy < 256u && (unsigned)gx < 256u)
        v = *(const s16x8*)(src + (size_t)(gy * 256 + gx) * cstr + cbase + cg * 8);
      *(s16x8*)&tile[pix * 40 + cg * 8] = v;
    }
    __syncthreads();

#pragma unroll
    for (int tap = 0; tap < 9; ++tap) {
      const int ky = tap / 3, kx = tap - ky * 3;
      const ushort_t* wb = wc + ((size_t)(tap * Kg + ch * 4 + quad) * 32 + l15) * 8;
      const s16x8 b0 = *(const s16x8*)wb;
      const s16x8 b1 = *(const s16x8*)(wb + 128);
#pragma unroll
      for (int r = 0; r < 4; ++r) {
        const int lr = 4 * wv + r + ky;
#pragma unroll
        for (int h = 0; h < 2; ++h) {
          const int lc = h * 16 + l15 + kx;
          const s16x8 a = *(const s16x8*)&tile[(lr * 34 + lc) * 40 + quad * 8];
          acc[r][h][0] = __builtin_amdgcn_mfma_f32_16x16x32_bf16(a, b0, acc[r][h][0], 0, 0, 0);
          acc[r][h][1] = __builtin_amdgcn_mfma_f32_16x16x32_bf16(a, b1, acc[r][h][1], 0, 0, 0);
        }
      }
    }
  }

  const float bv0 = bias[l15], bv1 = bias[16 + l15];
  ushort_t* on = outp + (size_t)n * (65536 * 32);
#pragma unroll
  for (int r = 0; r < 4; ++r) {
    const int gy = ty0 + 4 * wv + r;
#pragma unroll
    for (int h = 0; h < 2; ++h) {
#pragma unroll
      for (int i = 0; i < 4; ++i) {
        const int gx = tx0 + h * 16 + quad * 4 + i;
        ushort_t* op = on + (size_t)(gy * 256 + gx) * 32;
        op[l15]      = f2bf(fmaxf(acc[r][h][0][i] + bv0, 0.f));
        op[16 + l15] = f2bf(fmaxf(acc[r][h][1][i] + bv1, 0.f));
      }
    }
  }
}

// ---------------------------------------------------------------------------
// fuse: out = cat(f0..f3)[160] x Wf^T + bf + x (unchanged).
// ---------------------------------------------------------------------------
__global__ __launch_bounds__(256) void fuse_kernel(
    const ushort_t* __restrict__ f0, const ushort_t* __restrict__ f1,
    const ushort_t* __restrict__ f2, const ushort_t* __restrict__ f3,
    const float* __restrict__ x, const ushort_t* __restrict__ wff,
    const float* __restrict__ bfv, float* __restrict__ out)
{
  __shared__ float tr[4][64 * 17];

  const int tid = threadIdx.x, lane = tid & 63, wv = tid >> 6;
  const int quad = lane >> 4, l15 = lane & 15;

  s16x8 wf[5][4];
#pragma unroll
  for (int ks = 0; ks < 5; ++ks)
#pragma unroll
    for (int nt = 0; nt < 4; ++nt)
      wf[ks][nt] = *(const s16x8*)(wff + ((size_t)((ks * 4 + quad) * 64) + nt * 16 + l15) * 8);
  float bb[4];
#pragma unroll
  for (int nt = 0; nt < 4; ++nt) bb[nt] = bfv[nt * 16 + l15];

  const int wt = blockIdx.x * 4 + wv;
  const f32x4 zf = {0.f, 0.f, 0.f, 0.f};
  float* trw = tr[wv];

  for (int mt = 0; mt < 4; ++mt) {
    const int p0 = wt * 64 + mt * 16;
    const size_t pA = (size_t)(p0 + l15);
    const s16x8 a0 = *(const s16x8*)(f0 + pA * 64 + quad * 8);
    const s16x8 a1 = *(const s16x8*)(f0 + pA * 64 + 32 + quad * 8);
    const s16x8 a2 = *(const s16x8*)(f1 + pA * 32 + quad * 8);
    const s16x8 a3 = *(const s16x8*)(f2 + pA * 32 + quad * 8);
    const s16x8 a4 = *(const s16x8*)(f3 + pA * 32 + quad * 8);

    f32x4 acc[4];
#pragma unroll
    for (int nt = 0; nt < 4; ++nt) {
      f32x4 d = zf;
      d = __builtin_amdgcn_mfma_f32_16x16x32_bf16(a0, wf[0][nt], d, 0, 0, 0);
      d = __builtin_amdgcn_mfma_f32_16x16x32_bf16(a1, wf[1][nt], d, 0, 0, 0);
      d = __builtin_amdgcn_mfma_f32_16x16x32_bf16(a2, wf[2][nt], d, 0, 0, 0);
      d = __builtin_amdgcn_mfma_f32_16x16x32_bf16(a3, wf[3][nt], d, 0, 0, 0);
      d = __builtin_amdgcn_mfma_f32_16x16x32_bf16(a4, wf[4][nt], d, 0, 0, 0);
      acc[nt] = d;
    }

#pragma unroll
    for (int nt = 0; nt < 4; ++nt)
#pragma unroll
      for (int i = 0; i < 4; ++i)
        trw[(nt * 16 + l15) * 17 + quad * 4 + i] = acc[nt][i] + bb[nt];

    const int n = p0 >> 16;
    const int pix0 = p0 & 65535;
    const float* xb = x + (size_t)n * (64 * 65536);
    float* ob = out + (size_t)n * (64 * 65536);
#pragma unroll
    for (int og = 0; og < 16; ++og) {
      const int o = og * 4 + quad;
      const float v = trw[o * 17 + l15];
      const size_t g = (size_t)o * 65536 + pix0 + l15;
      ob[g] = v + xb[g];
    }
  }
}

// ---------------------------------------------------------------------------
extern "C" void kernel_launch(void* const* d_in, const int* in_sizes, int n_in,
                              void* d_out, int out_size, void* d_ws, size_t ws_size,
                              hipStream_t stream)
{
  const float* x     = (const float*)d_in[0];
  const float* Wq    = (const float*)d_in[1];
  const float* bq    = (const float*)d_in[2];
  const float* Wk    = (const float*)d_in[3];
  const float* bk    = (const float*)d_in[4];
  const float* Wv    = (const float*)d_in[5];
  const float* bv    = (const float*)d_in[6];
  const float* Wo    = (const float*)d_in[7];
  const float* bo    = (const float*)d_in[8];
  const float* gamma = (const float*)d_in[9];
  const float* W1    = (const float*)d_in[10];
  const float* b1    = (const float*)d_in[11];
  const float* W2    = (const float*)d_in[12];
  const float* b2    = (const float*)d_in[13];
  const float* W3    = (const float*)d_in[14];
  const float* b3    = (const float*)d_in[15];
  const float* Wf    = (const float*)d_in[16];
  const float* bf    = (const float*)d_in[17];

  float* out = (float*)d_out;
  ushort_t* wsu = (ushort_t*)d_ws;

  // bf16 feature buffers, pixel-major [n][y][x][c]
  ushort_t* f0 = wsu;                       // 16,777,216
  ushort_t* f1 = wsu + 16777216;            //  8,388,608
  ushort_t* f2 = wsu + 25165824;            //  8,388,608
  ushort_t* f3 = wsu + 33554432;            //  8,388,608
  // xt overlays f1+f2 (dead before conv1 writes f1);
  // kg/vt overlay f3 (dead before conv3 writes f3)
  ushort_t* xtb = wsu + 16777216;           // 16,777,216
  ushort_t* kgb = wsu + 33554432;           //  2,097,152
  ushort_t* vtb = wsu + 35651584;           //  2,097,152
  ushort_t* wc1 = wsu + 41943040;           // 18432
  ushort_t* wc2 = wc1 + 18432;              // 27648
  ushort_t* wc3 = wc2 + 27648;              // 36864
  ushort_t* wff = wc3 + 36864;              // 10240
  ushort_t* woq = wff + 10240;              // 2048
  ushort_t* wou = woq + 2048;               // 2048

  repack_kernel<<<144, 256, 0, stream>>>(W1, W2, W3, Wf, Wq, Wo,
                                         wc1, wc2, wc3, wff, woq, wou);
  kvx_kernel<<<1024, 256, 0, stream>>>(x, Wk, bk, Wv, bv, xtb, kgb, vtb);
  attn_kernel<<<512, 512, 0, stream>>>(xtb, kgb, vtb, woq, bq, wou, bo, gamma, f0);
  conv3_kernel<2><<<512, 256, 0, stream>>>(f0, f1, f2, wc1, b1, f1);
  conv3_kernel<3><<<512, 256, 0, stream>>>(f0, f1, f2, wc2, b2, f2);
  conv3_kernel<4><<<512, 256, 0, stream>>>(f0, f1, f2, wc3, b3, f3);
  fuse_kernel<<<1024, 256, 0, stream>>>(f0, f1, f2, f3, x, wff, bf, out);
}

// Round 3
// 331.388 us; speedup vs baseline: 1.0965x; 1.0965x over previous
//
#include <hip/hip_runtime.h>

// ============================================================================
// RegionNonLocalEnhancedDenseBlock on MI355X (gfx950) — Round 8
//  - r7 post-mortem: __launch_bounds__(512,4) is CUDA-semantics (min BLOCKS
//    per CU) on this hipcc -> 32 waves/CU -> 64-VGPR cap -> ~40 regs/thread
//    spilled to scratch (FETCH 195MB vs 70MB logical). Fix:
//      * __launch_bounds__(512, 2) -> 16 waves/CU -> 128-VGPR cap.
//      * exp/cvt_pk/shfl/PV fused per K-slice: pku[32] (32 live regs)
//        replaced by 4 transient words; St[] dies as consumed. Peak
//        pressure ~100 -> fits 128 with no spill.
//  - kvx (r6), conv3x3, fuse unchanged.
// ============================================================================

typedef short s16x8 __attribute__((ext_vector_type(8)));
typedef float f32x4 __attribute__((ext_vector_type(4)));
typedef unsigned short ushort_t;

__device__ __forceinline__ unsigned short f2bf(float f) {
  union { float f; unsigned int u; } v; v.f = f;
  unsigned int r = v.u + 0x7fffu + ((v.u >> 16) & 1u);  // RNE
  return (unsigned short)(r >> 16);
}
__device__ __forceinline__ float bf2f(unsigned short h) {
  union { unsigned int u; float f; } v; v.u = ((unsigned int)h) << 16;
  return v.f;
}
// packed f32x2 -> bf16x2 (RNE), lo = a, hi = b
__device__ __forceinline__ unsigned int cvtpk(float a, float b) {
  unsigned int r;
  asm("v_cvt_pk_bf16_f32 %0, %1, %2" : "=v"(r) : "v"(a), "v"(b));
  return r;
}

// ---------------------------------------------------------------------------
// Repack conv/fuse weights -> bf16 MFMA B-frag order; Wq/Wo -> linear bf16.
// ---------------------------------------------------------------------------
__global__ void repack_kernel(const float* __restrict__ W1, const float* __restrict__ W2,
                              const float* __restrict__ W3, const float* __restrict__ Wf,
                              const float* __restrict__ Wq, const float* __restrict__ Wo,
                              ushort_t* __restrict__ wc1, ushort_t* __restrict__ wc2,
                              ushort_t* __restrict__ wc3, ushort_t* __restrict__ wff,
                              ushort_t* __restrict__ woq, ushort_t* __restrict__ wou)
{
  const int i = blockIdx.x * 256 + threadIdx.x;
  if (i < 18432) {  // W1 [32][64][3][3], Kg=8
    int j = i & 7, o = (i >> 3) & 31, r = i >> 8, tap = r >> 3, kg = r & 7;
    wc1[i] = f2bf(W1[o * 576 + (kg * 8 + j) * 9 + tap]);
  }
  if (i < 27648) {  // W2 [32][96][3][3], Kg=12
    int j = i & 7, o = (i >> 3) & 31, r = i >> 8, tap = r / 12, kg = r % 12;
    wc2[i] = f2bf(W2[o * 864 + (kg * 8 + j) * 9 + tap]);
  }
  if (i < 36864) {  // W3 [32][128][3][3], Kg=16
    int j = i & 7, o = (i >> 3) & 31, r = i >> 8, tap = r >> 4, kg = r & 15;
    wc3[i] = f2bf(W3[o * 1152 + (kg * 8 + j) * 9 + tap]);
  }
  if (i < 10240) {  // Wf [64][160], Kg=20
    int j = i & 7, o = (i >> 3) & 63, kg = i >> 9;
    wff[i] = f2bf(Wf[o * 160 + kg * 8 + j]);
  }
  if (i < 2048) {   // Wq [32][64] linear, Wo [64][32] linear
    woq[i] = f2bf(Wq[i]);
    wou[i] = f2bf(Wo[i]);
  }
}

// ---------------------------------------------------------------------------
// kvx_kernel: grid 1024 = n(4) x pooled_row(128) x x_half(2). (unchanged r6)
// ---------------------------------------------------------------------------
__global__ __launch_bounds__(256, 4) void kvx_kernel(
    const float* __restrict__ x,
    const float* __restrict__ Wk, const float* __restrict__ bk,
    const float* __restrict__ Wv, const float* __restrict__ bv,
    ushort_t* __restrict__ xt, ushort_t* __restrict__ kg, ushort_t* __restrict__ vt)
{
  __shared__ __attribute__((aligned(16))) ushort_t lds[64 * 258];  // [c][258]
  __shared__ ushort_t kvs[4][8][64];  // [wave][kpos_local][K 0..31 | V 32..63]

  const int bid = blockIdx.x;
  const int n   = bid >> 8;
  const int rem = bid & 255;
  const int pr  = rem >> 1;            // pooled row 0..127
  const int xh  = rem & 1;             // x half
  const int tid = threadIdx.x, lane = tid & 63, wv = tid >> 6;
  const int quad = lane >> 4, l15 = lane & 15;

  const int y0 = pr * 2;
  const int x0 = xh * 128;
  const int gh = pr >> 4, pyc = pr & 15;

  const float* xblk = x + (size_t)n * (64 * 65536) + (size_t)(y0 * 256 + x0);
  ushort_t*    xtn  = xt + (size_t)n * (65536 * 64);

  // ---- phase 1: x -> LDS (coalesced 512B runs per instruction)
#pragma unroll 4
  for (int i = 0; i < 16; ++i) {
    const int idx = (i << 8) + tid;          // 0..4095 float4s
    const int c  = idx >> 6;                 // 64 float4 per channel
    const int r  = (idx >> 5) & 1;
    const int sg = idx & 31;
    const f32x4 v = *(const f32x4*)(xblk + (size_t)c * 65536 + r * 256 + sg * 4);
    const unsigned int lo = (unsigned int)f2bf(v[0]) | ((unsigned int)f2bf(v[1]) << 16);
    const unsigned int hi = (unsigned int)f2bf(v[2]) | ((unsigned int)f2bf(v[3]) << 16);
    const int base = c * 258 + (r << 7) + (sg << 2);   // u16 index, 4B aligned
    *(unsigned int*)&lds[base]     = lo;
    *(unsigned int*)&lds[base + 2] = hi;
  }

  // ---- K/V weight B-frags (L2-resident, overlaps phase-1 drain)
  s16x8 wkf[2][2], wvf[2][2];
#pragma unroll
  for (int ks = 0; ks < 2; ++ks)
#pragma unroll
    for (int nt = 0; nt < 2; ++nt) {
      const int off = (nt * 16 + l15) * 64 + ks * 32 + quad * 8;
      s16x8 tk, tv;
#pragma unroll
      for (int j = 0; j < 8; ++j) {
        tk[j] = (short)f2bf(Wk[off + j]);
        tv[j] = (short)f2bf(Wv[off + j]);
      }
      wkf[ks][nt] = tk; wvf[ks][nt] = tv;
    }
  float bkv[2], bvv[2];
#pragma unroll
  for (int nt = 0; nt < 2; ++nt) {
    bkv[nt] = bk[nt * 16 + l15];
    bvv[nt] = bv[nt * 16 + l15];
  }

  __syncthreads();

  // ---- phase 2a: xt stores — lane = (pixel_octet, ch_octet); 1KB contiguous
  {
    const int g  = lane & 7;        // channel octet
    const int pa = lane >> 3;       // pixel within octet run
#pragma unroll
    for (int s = 0; s < 8; ++s) {
      const int p = (wv << 6) + (s << 3) + pa;        // 0..255 local pixel
      s16x8 v;
#pragma unroll
      for (int j = 0; j < 8; ++j) v[j] = (short)lds[(g * 8 + j) * 258 + p];
      const int P = (y0 + (p >> 7)) * 256 + x0 + (p & 127);
      *(s16x8*)(xtn + (size_t)P * 64 + g * 8) = v;
    }
  }

  // ---- phase 2b: K/V — 2 x-tiles (16px) per wave, both rows, pool 2x2
  const f32x4 zf = {0.f, 0.f, 0.f, 0.f};
#pragma unroll
  for (int tt = 0; tt < 2; ++tt) {
    const int t   = wv * 2 + tt;          // x-tile 0..7 (local)
    const int px0 = t * 16 + l15;

    s16x8 a[2][2];                        // [row][ks]
#pragma unroll
    for (int r = 0; r < 2; ++r)
#pragma unroll
      for (int ks = 0; ks < 2; ++ks) {
        s16x8 v;
#pragma unroll
        for (int j = 0; j < 8; ++j)
          v[j] = (short)lds[(ks * 32 + quad * 8 + j) * 258 + (r << 7) + px0];
        a[r][ks] = v;
      }

    f32x4 kd[2][2], vd[2][2];             // [row][nt]
#pragma unroll
    for (int r = 0; r < 2; ++r)
#pragma unroll
      for (int nt = 0; nt < 2; ++nt) {
        f32x4 k0 = __builtin_amdgcn_mfma_f32_16x16x32_bf16(a[r][0], wkf[0][nt], zf, 0, 0, 0);
        kd[r][nt] = __builtin_amdgcn_mfma_f32_16x16x32_bf16(a[r][1], wkf[1][nt], k0, 0, 0, 0);
        f32x4 v0 = __builtin_amdgcn_mfma_f32_16x16x32_bf16(a[r][0], wvf[0][nt], zf, 0, 0, 0);
        vd[r][nt] = __builtin_amdgcn_mfma_f32_16x16x32_bf16(a[r][1], wvf[1][nt], v0, 0, 0, 0);
      }

    // pool 2x2 (x-pairs are adjacent D-rows = adjacent regs; y-pairs = r)
#pragma unroll
    for (int nt = 0; nt < 2; ++nt)
#pragma unroll
      for (int rr = 0; rr < 2; ++rr) {
        const float kp = fmaxf(fmaxf(kd[0][nt][2 * rr], kd[0][nt][2 * rr + 1]),
                               fmaxf(kd[1][nt][2 * rr], kd[1][nt][2 * rr + 1])) + bkv[nt];
        const float vp = fmaxf(fmaxf(vd[0][nt][2 * rr], vd[0][nt][2 * rr + 1]),
                               fmaxf(vd[1][nt][2 * rr], vd[1][nt][2 * rr + 1])) + bvv[nt];
        kvs[wv][quad * 2 + rr][nt * 16 + l15]      = f2bf(kp);
        kvs[wv][quad * 2 + rr][32 + nt * 16 + l15] = f2bf(vp);
      }

    const int gw    = xh * 4 + (t >> 1);
    const int cell  = (n << 6) + (gh << 3) + gw;
    const int kposb = pyc * 16 + (t & 1) * 8;
    if (lane < 32) {
      const s16x8 vv = *(const s16x8*)&kvs[wv][lane >> 2][(lane & 3) * 8];
      *(s16x8*)(kg + ((size_t)(cell << 8) + kposb + (lane >> 2)) * 32 + (lane & 3) * 8) = vv;
    } else {
      const int ch = lane - 32;
      s16x8 vv;
#pragma unroll
      for (int r = 0; r < 8; ++r) vv[r] = (short)kvs[wv][r][32 + ch];
      *(s16x8*)(vt + (size_t)(cell << 13) + ch * 256 + kposb) = vv;
    }
  }
}

// ---------------------------------------------------------------------------
// attn_kernel v4: grid 512 (2 blocks/cell), 8 waves, 4 M-tiles/wave.
// Swapped S^T = mfma(K,Q); exp/pack/shfl/PV fused per K-slice (low VGPR).
// ---------------------------------------------------------------------------
__global__ __launch_bounds__(512, 2) void attn_kernel(
    const ushort_t* __restrict__ xt, const ushort_t* __restrict__ kg,
    const ushort_t* __restrict__ vt,
    const ushort_t* __restrict__ woq, const float* __restrict__ bq,
    const ushort_t* __restrict__ wou, const float* __restrict__ bo,
    const float* __restrict__ gamma_p, ushort_t* __restrict__ f0)
{
  __shared__ __attribute__((aligned(16))) ushort_t kl[256 * 36];  // K [kpos][32] pad36
  __shared__ __attribute__((aligned(16))) ushort_t vl[32 * 268];  // V^T [ch][256] pad268
  __shared__ __attribute__((aligned(16))) ushort_t un[8][1152];   // per-wave scratch

  const int bid = blockIdx.x;
  const int cell = bid >> 1;
  const int part = bid & 1;
  const int tid = threadIdx.x, lane = tid & 63, wv = tid >> 6;
  const int quad = lane >> 4, l15 = lane & 15;

  const int n  = cell >> 6;
  const int gh = (cell >> 3) & 7;
  const int gw = cell & 7;
  const int y0 = gh * 32, xc0 = gw * 32;

  const ushort_t* xtn = xt + (size_t)n * (65536 * 64);
  ushort_t*       f0n = f0 + (size_t)n * (65536 * 64);
  const ushort_t* kc  = kg + (size_t)(cell << 8) * 32;
  const ushort_t* vc  = vt + (size_t)(cell << 13);

  // ---- stage K and V^T into LDS (one pass, b128 both sides)
  for (int idx = tid; idx < 1024; idx += 512) {
    const int kpos = idx >> 2, cg = idx & 3;
    *(s16x8*)&kl[kpos * 36 + cg * 8] = *(const s16x8*)(kc + kpos * 32 + cg * 8);
  }
  for (int idx = tid; idx < 1024; idx += 512) {
    const int ch = idx >> 5, seg = idx & 31;
    *(s16x8*)&vl[ch * 268 + seg * 8] = *(const s16x8*)(vc + ch * 256 + seg * 8);
  }

  const float gamma = gamma_p[0];

  // Wq B-frags from repacked bf16 (resident; Wo loaded at use)
  s16x8 wqf[2][2];
#pragma unroll
  for (int ks = 0; ks < 2; ++ks)
#pragma unroll
    for (int nt = 0; nt < 2; ++nt)
      wqf[ks][nt] = *(const s16x8*)(woq + (nt * 16 + l15) * 64 + ks * 32 + quad * 8);
  float bqv[2]; bqv[0] = bq[l15]; bqv[1] = bq[16 + l15];
  float bov[4];
#pragma unroll
  for (int nt = 0; nt < 4; ++nt) bov[nt] = bo[nt * 16 + l15];

  __syncthreads();   // K/V staged

  ushort_t* uw = un[wv];
  const f32x4 zf = {0.f, 0.f, 0.f, 0.f};

  // shuffle geometry for P redistribution
  const int src0 = ((quad & 1) << 5) + l15;   // lane (l15, 2*(quad&1))
  const int src1 = src0 + 16;                 // lane (l15, 2*(quad&1)+1)
  const int hsel = quad >> 1;                 // selects hi/lo pk pair

#pragma unroll 1
  for (int it = 0; it < 4; ++it) {
    const int mt = part * 32 + wv * 4 + it;   // 0..63
    const int pbase = mt * 16;

    const int p = pbase + l15;
    const int yy = p >> 5, xx = p & 31;
    const size_t pixg = (size_t)((y0 + yy) * 256 + xc0 + xx);

    // ---- Q-gen from xt
    const s16x8 a0 = *(const s16x8*)(xtn + pixg * 64 + quad * 8);
    const s16x8 a1 = *(const s16x8*)(xtn + pixg * 64 + 32 + quad * 8);
    f32x4 qd0 = zf, qd1 = zf;
    qd0 = __builtin_amdgcn_mfma_f32_16x16x32_bf16(a0, wqf[0][0], qd0, 0, 0, 0);
    qd0 = __builtin_amdgcn_mfma_f32_16x16x32_bf16(a1, wqf[1][0], qd0, 0, 0, 0);
    qd1 = __builtin_amdgcn_mfma_f32_16x16x32_bf16(a0, wqf[0][1], qd1, 0, 0, 0);
    qd1 = __builtin_amdgcn_mfma_f32_16x16x32_bf16(a1, wqf[1][1], qd1, 0, 0, 0);
    // qt phase of union buffer (stride 40)
#pragma unroll
    for (int i = 0; i < 4; ++i) {
      uw[(quad * 4 + i) * 40 + l15]      = f2bf(qd0[i] + bqv[0]);
      uw[(quad * 4 + i) * 40 + 16 + l15] = f2bf(qd1[i] + bqv[1]);
    }
    const s16x8 qa = *(const s16x8*)&uw[l15 * 40 + quad * 8];

    // ---- S^T = K.Q^T (swapped): lane (l15,q) reg i of tile nt holds
    //      S[kpos = 16nt+4q+i][qpix = l15]
    f32x4 St[16];
#pragma unroll
    for (int nt = 0; nt < 16; ++nt) {
      const s16x8 kb = *(const s16x8*)&kl[(nt * 16 + l15) * 36 + quad * 8];
      St[nt] = __builtin_amdgcn_mfma_f32_16x16x32_bf16(kb, qa, zf, 0, 0, 0);
    }

    // ---- global max over 256 kpos for qpix=l15
    float m = St[0][0];
#pragma unroll
    for (int nt = 0; nt < 16; ++nt) {
      m = fmaxf(m, fmaxf(fmaxf(St[nt][0], St[nt][1]), fmaxf(St[nt][2], St[nt][3])));
    }
    m = fmaxf(m, __shfl_xor(m, 16, 64));
    m = fmaxf(m, __shfl_xor(m, 32, 64));

    // ---- fused exp -> cvt_pk -> shfl -> PV MFMA per K-slice (32 kpos).
    // pk words live only within a slice: peak VGPR ~100 (no spill @128 cap).
    float s = 0.f;
    f32x4 O0 = zf, O1 = zf;
#pragma unroll
    for (int kk = 0; kk < 8; ++kk) {
      const float e0 = __expf(St[2 * kk][0] - m);
      const float e1 = __expf(St[2 * kk][1] - m);
      const float e2 = __expf(St[2 * kk][2] - m);
      const float e3 = __expf(St[2 * kk][3] - m);
      const float g0 = __expf(St[2 * kk + 1][0] - m);
      const float g1 = __expf(St[2 * kk + 1][1] - m);
      const float g2 = __expf(St[2 * kk + 1][2] - m);
      const float g3 = __expf(St[2 * kk + 1][3] - m);
      s += ((e0 + e1) + (e2 + e3)) + ((g0 + g1) + (g2 + g3));
      const unsigned int pk0 = cvtpk(e0, e1);   // nt=2kk   kpos {+0,+1}
      const unsigned int pk1 = cvtpk(e2, e3);   // nt=2kk   kpos {+2,+3}
      const unsigned int pk2 = cvtpk(g0, g1);   // nt=2kk+1 kpos {+0,+1}
      const unsigned int pk3 = cvtpk(g2, g3);   // nt=2kk+1 kpos {+2,+3}
      // target lane (l15,q') word w needs pk[(q'>>1) pair][w&1] from lane
      // (l15, 2(q'&1) + (w>>1)).
      const int A0 = __shfl((int)pk0, src0, 64);
      const int B0 = __shfl((int)pk2, src0, 64);
      const int A1 = __shfl((int)pk1, src0, 64);
      const int B1 = __shfl((int)pk3, src0, 64);
      const int A2 = __shfl((int)pk0, src1, 64);
      const int B2 = __shfl((int)pk2, src1, 64);
      const int A3 = __shfl((int)pk1, src1, 64);
      const int B3 = __shfl((int)pk3, src1, 64);
      union { int w[4]; s16x8 v; } pa;
      pa.w[0] = hsel ? B0 : A0;
      pa.w[1] = hsel ? B1 : A1;
      pa.w[2] = hsel ? B2 : A2;
      pa.w[3] = hsel ? B3 : A3;
      const int kb0 = kk * 32 + quad * 8;
      const s16x8 vb0 = *(const s16x8*)&vl[l15 * 268 + kb0];
      const s16x8 vb1 = *(const s16x8*)&vl[(16 + l15) * 268 + kb0];
      O0 = __builtin_amdgcn_mfma_f32_16x16x32_bf16(pa.v, vb0, O0, 0, 0, 0);
      O1 = __builtin_amdgcn_mfma_f32_16x16x32_bf16(pa.v, vb1, O1, 0, 0, 0);
    }
    s += __shfl_xor(s, 16, 64);
    s += __shfl_xor(s, 32, 64);

    // row sums for this lane's O rows (qpix = 4*quad+i)
    float rv[4];
#pragma unroll
    for (int i = 0; i < 4; ++i) rv[i] = __shfl(s, quad * 4 + i, 64);

    // ---- normalize, C->A (ot phase, stride 40), project Wo
#pragma unroll
    for (int i = 0; i < 4; ++i) {
      const float inv = 1.0f / rv[i];
      uw[(quad * 4 + i) * 40 + l15]      = f2bf(O0[i] * inv);
      uw[(quad * 4 + i) * 40 + 16 + l15] = f2bf(O1[i] * inv);
    }
    const s16x8 oa = *(const s16x8*)&uw[l15 * 40 + quad * 8];
    // ft phase (stride 72): [q][64ch]; Wo B-frags loaded at use (L2-hot)
#pragma unroll
    for (int nt = 0; nt < 4; ++nt) {
      const s16x8 wofn = *(const s16x8*)(wou + (nt * 16 + l15) * 32 + quad * 8);
      f32x4 D = __builtin_amdgcn_mfma_f32_16x16x32_bf16(oa, wofn, zf, 0, 0, 0);
#pragma unroll
      for (int i = 0; i < 4; ++i)
        uw[(quad * 4 + i) * 72 + nt * 16 + l15] = f2bf(gamma * (D[i] + bov[nt]));
    }

    // ---- epilogue: +xt residual, packed cvt, 16B vector stores
    {
      const s16x8 fv0 = *(const s16x8*)&uw[l15 * 72 + quad * 16];
      const s16x8 fv1 = *(const s16x8*)&uw[l15 * 72 + quad * 16 + 8];
      const s16x8 xv0 = *(const s16x8*)(xtn + pixg * 64 + quad * 16);
      const s16x8 xv1 = *(const s16x8*)(xtn + pixg * 64 + quad * 16 + 8);
      union { unsigned int w[4]; s16x8 v; } r0, r1;
#pragma unroll
      for (int k = 0; k < 4; ++k) {
        const float p0 = bf2f((unsigned short)fv0[2 * k])     + bf2f((unsigned short)xv0[2 * k]);
        const float p1 = bf2f((unsigned short)fv0[2 * k + 1]) + bf2f((unsigned short)xv0[2 * k + 1]);
        const float p2 = bf2f((unsigned short)fv1[2 * k])     + bf2f((unsigned short)xv1[2 * k]);
        const float p3 = bf2f((unsigned short)fv1[2 * k + 1]) + bf2f((unsigned short)xv1[2 * k + 1]);
        r0.w[k] = cvtpk(p0, p1);
        r1.w[k] = cvtpk(p2, p3);
      }
      *(s16x8*)(f0n + pixg * 64 + quad * 16)     = r0.v;
      *(s16x8*)(f0n + pixg * 64 + quad * 16 + 8) = r1.v;
    }
  }
}

// ---------------------------------------------------------------------------
// conv3x3 + ReLU via bf16 MFMA implicit GEMM (unchanged).
// ---------------------------------------------------------------------------
template <int NCHUNK>
__global__ __launch_bounds__(256) void conv3_kernel(
    const ushort_t* __restrict__ s0, const ushort_t* __restrict__ s1,
    const ushort_t* __restrict__ s2, const ushort_t* __restrict__ wc,
    const float* __restrict__ bias, ushort_t* __restrict__ outp)
{
  __shared__ __attribute__((aligned(16))) ushort_t tile[612 * 40];

  const int bid = blockIdx.x;
  const int n = bid >> 7;
  const int t = bid & 127;
  const int ty0 = (t >> 3) * 16;
  const int tx0 = (t & 7) * 32;
  const int tid = threadIdx.x, lane = tid & 63, wv = tid >> 6;
  const int quad = lane >> 4, l15 = lane & 15;
  constexpr int Kg = NCHUNK * 4;

  const f32x4 zf = {0.f, 0.f, 0.f, 0.f};
  f32x4 acc[4][2][2];
#pragma unroll
  for (int r = 0; r < 4; ++r)
#pragma unroll
    for (int h = 0; h < 2; ++h) { acc[r][h][0] = zf; acc[r][h][1] = zf; }

  for (int ch = 0; ch < NCHUNK; ++ch) {
    const ushort_t* src; int cstr, cbase;
    if (ch < 2)       { src = s0 + (size_t)n * (65536 * 64); cstr = 64; cbase = ch * 32; }
    else if (ch == 2) { src = s1 + (size_t)n * (65536 * 32); cstr = 32; cbase = 0; }
    else              { src = s2 + (size_t)n * (65536 * 32); cstr = 32; cbase = 0; }

    __syncthreads();
    for (int u = tid; u < 2448; u += 256) {
      const int pix = u >> 2, cg = u & 3;
      const int lr = pix / 34, lc = pix - lr * 34;
      const int gy = ty0 - 1 + lr, gx = tx0 - 1 + lc;
      s16x8 v = {0, 0, 0, 0, 0, 0, 0, 0};
      if ((unsigned)gy < 256u && (unsigned)gx < 256u)
        v = *(const s16x8*)(src + (size_t)(gy * 256 + gx) * cstr + cbase + cg * 8);
      *(s16x8*)&tile[pix * 40 + cg * 8] = v;
    }
    __syncthreads();

#pragma unroll
    for (int tap = 0; tap < 9; ++tap) {
      const int ky = tap / 3, kx = tap - ky * 3;
      const ushort_t* wb = wc + ((size_t)(tap * Kg + ch * 4 + quad) * 32 + l15) * 8;
      const s16x8 b0 = *(const s16x8*)wb;
      const s16x8 b1 = *(const s16x8*)(wb + 128);
#pragma unroll
      for (int r = 0; r < 4; ++r) {
        const int lr = 4 * wv + r + ky;
#pragma unroll
        for (int h = 0; h < 2; ++h) {
          const int lc = h * 16 + l15 + kx;
          const s16x8 a = *(const s16x8*)&tile[(lr * 34 + lc) * 40 + quad * 8];
          acc[r][h][0] = __builtin_amdgcn_mfma_f32_16x16x32_bf16(a, b0, acc[r][h][0], 0, 0, 0);
          acc[r][h][1] = __builtin_amdgcn_mfma_f32_16x16x32_bf16(a, b1, acc[r][h][1], 0, 0, 0);
        }
      }
    }
  }

  const float bv0 = bias[l15], bv1 = bias[16 + l15];
  ushort_t* on = outp + (size_t)n * (65536 * 32);
#pragma unroll
  for (int r = 0; r < 4; ++r) {
    const int gy = ty0 + 4 * wv + r;
#pragma unroll
    for (int h = 0; h < 2; ++h) {
#pragma unroll
      for (int i = 0; i < 4; ++i) {
        const int gx = tx0 + h * 16 + quad * 4 + i;
        ushort_t* op = on + (size_t)(gy * 256 + gx) * 32;
        op[l15]      = f2bf(fmaxf(acc[r][h][0][i] + bv0, 0.f));
        op[16 + l15] = f2bf(fmaxf(acc[r][h][1][i] + bv1, 0.f));
      }
    }
  }
}

// ---------------------------------------------------------------------------
// fuse: out = cat(f0..f3)[160] x Wf^T + bf + x (unchanged).
// ---------------------------------------------------------------------------
__global__ __launch_bounds__(256) void fuse_kernel(
    const ushort_t* __restrict__ f0, const ushort_t* __restrict__ f1,
    const ushort_t* __restrict__ f2, const ushort_t* __restrict__ f3,
    const float* __restrict__ x, const ushort_t* __restrict__ wff,
    const float* __restrict__ bfv, float* __restrict__ out)
{
  __shared__ float tr[4][64 * 17];

  const int tid = threadIdx.x, lane = tid & 63, wv = tid >> 6;
  const int quad = lane >> 4, l15 = lane & 15;

  s16x8 wf[5][4];
#pragma unroll
  for (int ks = 0; ks < 5; ++ks)
#pragma unroll
    for (int nt = 0; nt < 4; ++nt)
      wf[ks][nt] = *(const s16x8*)(wff + ((size_t)((ks * 4 + quad) * 64) + nt * 16 + l15) * 8);
  float bb[4];
#pragma unroll
  for (int nt = 0; nt < 4; ++nt) bb[nt] = bfv[nt * 16 + l15];

  const int wt = blockIdx.x * 4 + wv;
  const f32x4 zf = {0.f, 0.f, 0.f, 0.f};
  float* trw = tr[wv];

  for (int mt = 0; mt < 4; ++mt) {
    const int p0 = wt * 64 + mt * 16;
    const size_t pA = (size_t)(p0 + l15);
    const s16x8 a0 = *(const s16x8*)(f0 + pA * 64 + quad * 8);
    const s16x8 a1 = *(const s16x8*)(f0 + pA * 64 + 32 + quad * 8);
    const s16x8 a2 = *(const s16x8*)(f1 + pA * 32 + quad * 8);
    const s16x8 a3 = *(const s16x8*)(f2 + pA * 32 + quad * 8);
    const s16x8 a4 = *(const s16x8*)(f3 + pA * 32 + quad * 8);

    f32x4 acc[4];
#pragma unroll
    for (int nt = 0; nt < 4; ++nt) {
      f32x4 d = zf;
      d = __builtin_amdgcn_mfma_f32_16x16x32_bf16(a0, wf[0][nt], d, 0, 0, 0);
      d = __builtin_amdgcn_mfma_f32_16x16x32_bf16(a1, wf[1][nt], d, 0, 0, 0);
      d = __builtin_amdgcn_mfma_f32_16x16x32_bf16(a2, wf[2][nt], d, 0, 0, 0);
      d = __builtin_amdgcn_mfma_f32_16x16x32_bf16(a3, wf[3][nt], d, 0, 0, 0);
      d = __builtin_amdgcn_mfma_f32_16x16x32_bf16(a4, wf[4][nt], d, 0, 0, 0);
      acc[nt] = d;
    }

#pragma unroll
    for (int nt = 0; nt < 4; ++nt)
#pragma unroll
      for (int i = 0; i < 4; ++i)
        trw[(nt * 16 + l15) * 17 + quad * 4 + i] = acc[nt][i] + bb[nt];

    const int n = p0 >> 16;
    const int pix0 = p0 & 65535;
    const float* xb = x + (size_t)n * (64 * 65536);
    float* ob = out + (size_t)n * (64 * 65536);
#pragma unroll
    for (int og = 0; og < 16; ++og) {
      const int o = og * 4 + quad;
      const float v = trw[o * 17 + l15];
      const size_t g = (size_t)o * 65536 + pix0 + l15;
      ob[g] = v + xb[g];
    }
  }
}

// ---------------------------------------------------------------------------
extern "C" void kernel_launch(void* const* d_in, const int* in_sizes, int n_in,
                              void* d_out, int out_size, void* d_ws, size_t ws_size,
                              hipStream_t stream)
{
  const float* x     = (const float*)d_in[0];
  const float* Wq    = (const float*)d_in[1];
  const float* bq    = (const float*)d_in[2];
  const float* Wk    = (const float*)d_in[3];
  const float* bk    = (const float*)d_in[4];
  const float* Wv    = (const float*)d_in[5];
  const float* bv    = (const float*)d_in[6];
  const float* Wo    = (const float*)d_in[7];
  const float* bo    = (const float*)d_in[8];
  const float* gamma = (const float*)d_in[9];
  const float* W1    = (const float*)d_in[10];
  const float* b1    = (const float*)d_in[11];
  const float* W2    = (const float*)d_in[12];
  const float* b2    = (const float*)d_in[13];
  const float* W3    = (const float*)d_in[14];
  const float* b3    = (const float*)d_in[15];
  const float* Wf    = (const float*)d_in[16];
  const float* bf    = (const float*)d_in[17];

  float* out = (float*)d_out;
  ushort_t* wsu = (ushort_t*)d_ws;

  // bf16 feature buffers, pixel-major [n][y][x][c]
  ushort_t* f0 = wsu;                       // 16,777,216
  ushort_t* f1 = wsu + 16777216;            //  8,388,608
  ushort_t* f2 = wsu + 25165824;            //  8,388,608
  ushort_t* f3 = wsu + 33554432;            //  8,388,608
  // xt overlays f1+f2 (dead before conv1 writes f1);
  // kg/vt overlay f3 (dead before conv3 writes f3)
  ushort_t* xtb = wsu + 16777216;           // 16,777,216
  ushort_t* kgb = wsu + 33554432;           //  2,097,152
  ushort_t* vtb = wsu + 35651584;           //  2,097,152
  ushort_t* wc1 = wsu + 41943040;           // 18432
  ushort_t* wc2 = wc1 + 18432;              // 27648
  ushort_t* wc3 = wc2 + 27648;              // 36864
  ushort_t* wff = wc3 + 36864;              // 10240
  ushort_t* woq = wff + 10240;              // 2048
  ushort_t* wou = woq + 2048;               // 2048

  repack_kernel<<<144, 256, 0, stream>>>(W1, W2, W3, Wf, Wq, Wo,
                                         wc1, wc2, wc3, wff, woq, wou);
  kvx_kernel<<<1024, 256, 0, stream>>>(x, Wk, bk, Wv, bv, xtb, kgb, vtb);
  attn_kernel<<<512, 512, 0, stream>>>(xtb, kgb, vtb, woq, bq, wou, bo, gamma, f0);
  conv3_kernel<2><<<512, 256, 0, stream>>>(f0, f1, f2, wc1, b1, f1);
  conv3_kernel<3><<<512, 256, 0, stream>>>(f0, f1, f2, wc2, b2, f2);
  conv3_kernel<4><<<512, 256, 0, stream>>>(f0, f1, f2, wc3, b3, f3);
  fuse_kernel<<<1024, 256, 0, stream>>>(f0, f1, f2, f3, x, wff, bf, out);
}

// Round 5
// 316.575 us; speedup vs baseline: 1.1478x; 1.0468x over previous
//
#include <hip/hip_runtime.h>

// ============================================================================
// RegionNonLocalEnhancedDenseBlock on MI355X (gfx950) — Round 10
//  - r9 post-mortem: swapped-everything attn (v5) produced NaN; algebra
//    re-verified clean, bug not isolatable one-shot -> REVERTED to r8 attn v4
//    (proven: 52.8us, total 331us).
//  - conv3_kernel improved (theory-backed, low risk):
//      * staging: precomputed slots, 10 batched global loads -> 10 ds_writes
//        (breaks the ~10x serial L3-latency chain per chunk)
//      * epilogue: acc -> LDS transpose -> 8x b128 coalesced stores
//        (replaces 64 scalar u16 global stores per thread)
//  - kvx (r6), attn (r8), fuse, repack (r8) unchanged.
// ============================================================================

typedef short s16x8 __attribute__((ext_vector_type(8)));
typedef float f32x4 __attribute__((ext_vector_type(4)));
typedef unsigned short ushort_t;

__device__ __forceinline__ unsigned short f2bf(float f) {
  union { float f; unsigned int u; } v; v.f = f;
  unsigned int r = v.u + 0x7fffu + ((v.u >> 16) & 1u);  // RNE
  return (unsigned short)(r >> 16);
}
__device__ __forceinline__ float bf2f(unsigned short h) {
  union { unsigned int u; float f; } v; v.u = ((unsigned int)h) << 16;
  return v.f;
}
// packed f32x2 -> bf16x2 (RNE), lo = a, hi = b
__device__ __forceinline__ unsigned int cvtpk(float a, float b) {
  unsigned int r;
  asm("v_cvt_pk_bf16_f32 %0, %1, %2" : "=v"(r) : "v"(a), "v"(b));
  return r;
}

// ---------------------------------------------------------------------------
// Repack conv/fuse weights -> bf16 MFMA B-frag order; Wq/Wo -> linear bf16.
// ---------------------------------------------------------------------------
__global__ void repack_kernel(const float* __restrict__ W1, const float* __restrict__ W2,
                              const float* __restrict__ W3, const float* __restrict__ Wf,
                              const float* __restrict__ Wq, const float* __restrict__ Wo,
                              ushort_t* __restrict__ wc1, ushort_t* __restrict__ wc2,
                              ushort_t* __restrict__ wc3, ushort_t* __restrict__ wff,
                              ushort_t* __restrict__ woq, ushort_t* __restrict__ wou)
{
  const int i = blockIdx.x * 256 + threadIdx.x;
  if (i < 18432) {  // W1 [32][64][3][3], Kg=8
    int j = i & 7, o = (i >> 3) & 31, r = i >> 8, tap = r >> 3, kg = r & 7;
    wc1[i] = f2bf(W1[o * 576 + (kg * 8 + j) * 9 + tap]);
  }
  if (i < 27648) {  // W2 [32][96][3][3], Kg=12
    int j = i & 7, o = (i >> 3) & 31, r = i >> 8, tap = r / 12, kg = r % 12;
    wc2[i] = f2bf(W2[o * 864 + (kg * 8 + j) * 9 + tap]);
  }
  if (i < 36864) {  // W3 [32][128][3][3], Kg=16
    int j = i & 7, o = (i >> 3) & 31, r = i >> 8, tap = r >> 4, kg = r & 15;
    wc3[i] = f2bf(W3[o * 1152 + (kg * 8 + j) * 9 + tap]);
  }
  if (i < 10240) {  // Wf [64][160], Kg=20
    int j = i & 7, o = (i >> 3) & 63, kg = i >> 9;
    wff[i] = f2bf(Wf[o * 160 + kg * 8 + j]);
  }
  if (i < 2048) {   // Wq [32][64] linear, Wo [64][32] linear
    woq[i] = f2bf(Wq[i]);
    wou[i] = f2bf(Wo[i]);
  }
}

// ---------------------------------------------------------------------------
// kvx_kernel: grid 1024 = n(4) x pooled_row(128) x x_half(2). (unchanged r6)
// ---------------------------------------------------------------------------
__global__ __launch_bounds__(256, 4) void kvx_kernel(
    const float* __restrict__ x,
    const float* __restrict__ Wk, const float* __restrict__ bk,
    const float* __restrict__ Wv, const float* __restrict__ bv,
    ushort_t* __restrict__ xt, ushort_t* __restrict__ kg, ushort_t* __restrict__ vt)
{
  __shared__ __attribute__((aligned(16))) ushort_t lds[64 * 258];  // [c][258]
  __shared__ ushort_t kvs[4][8][64];  // [wave][kpos_local][K 0..31 | V 32..63]

  const int bid = blockIdx.x;
  const int n   = bid >> 8;
  const int rem = bid & 255;
  const int pr  = rem >> 1;            // pooled row 0..127
  const int xh  = rem & 1;             // x half
  const int tid = threadIdx.x, lane = tid & 63, wv = tid >> 6;
  const int quad = lane >> 4, l15 = lane & 15;

  const int y0 = pr * 2;
  const int x0 = xh * 128;
  const int gh = pr >> 4, pyc = pr & 15;

  const float* xblk = x + (size_t)n * (64 * 65536) + (size_t)(y0 * 256 + x0);
  ushort_t*    xtn  = xt + (size_t)n * (65536 * 64);

  // ---- phase 1: x -> LDS (coalesced 512B runs per instruction)
#pragma unroll 4
  for (int i = 0; i < 16; ++i) {
    const int idx = (i << 8) + tid;          // 0..4095 float4s
    const int c  = idx >> 6;                 // 64 float4 per channel
    const int r  = (idx >> 5) & 1;
    const int sg = idx & 31;
    const f32x4 v = *(const f32x4*)(xblk + (size_t)c * 65536 + r * 256 + sg * 4);
    const unsigned int lo = (unsigned int)f2bf(v[0]) | ((unsigned int)f2bf(v[1]) << 16);
    const unsigned int hi = (unsigned int)f2bf(v[2]) | ((unsigned int)f2bf(v[3]) << 16);
    const int base = c * 258 + (r << 7) + (sg << 2);   // u16 index, 4B aligned
    *(unsigned int*)&lds[base]     = lo;
    *(unsigned int*)&lds[base + 2] = hi;
  }

  // ---- K/V weight B-frags (L2-resident, overlaps phase-1 drain)
  s16x8 wkf[2][2], wvf[2][2];
#pragma unroll
  for (int ks = 0; ks < 2; ++ks)
#pragma unroll
    for (int nt = 0; nt < 2; ++nt) {
      const int off = (nt * 16 + l15) * 64 + ks * 32 + quad * 8;
      s16x8 tk, tv;
#pragma unroll
      for (int j = 0; j < 8; ++j) {
        tk[j] = (short)f2bf(Wk[off + j]);
        tv[j] = (short)f2bf(Wv[off + j]);
      }
      wkf[ks][nt] = tk; wvf[ks][nt] = tv;
    }
  float bkv[2], bvv[2];
#pragma unroll
  for (int nt = 0; nt < 2; ++nt) {
    bkv[nt] = bk[nt * 16 + l15];
    bvv[nt] = bv[nt * 16 + l15];
  }

  __syncthreads();

  // ---- phase 2a: xt stores — lane = (pixel_octet, ch_octet); 1KB contiguous
  {
    const int g  = lane & 7;        // channel octet
    const int pa = lane >> 3;       // pixel within octet run
#pragma unroll
    for (int s = 0; s < 8; ++s) {
      const int p = (wv << 6) + (s << 3) + pa;        // 0..255 local pixel
      s16x8 v;
#pragma unroll
      for (int j = 0; j < 8; ++j) v[j] = (short)lds[(g * 8 + j) * 258 + p];
      const int P = (y0 + (p >> 7)) * 256 + x0 + (p & 127);
      *(s16x8*)(xtn + (size_t)P * 64 + g * 8) = v;
    }
  }

  // ---- phase 2b: K/V — 2 x-tiles (16px) per wave, both rows, pool 2x2
  const f32x4 zf = {0.f, 0.f, 0.f, 0.f};
#pragma unroll
  for (int tt = 0; tt < 2; ++tt) {
    const int t   = wv * 2 + tt;          // x-tile 0..7 (local)
    const int px0 = t * 16 + l15;

    s16x8 a[2][2];                        // [row][ks]
#pragma unroll
    for (int r = 0; r < 2; ++r)
#pragma unroll
      for (int ks = 0; ks < 2; ++ks) {
        s16x8 v;
#pragma unroll
        for (int j = 0; j < 8; ++j)
          v[j] = (short)lds[(ks * 32 + quad * 8 + j) * 258 + (r << 7) + px0];
        a[r][ks] = v;
      }

    f32x4 kd[2][2], vd[2][2];             // [row][nt]
#pragma unroll
    for (int r = 0; r < 2; ++r)
#pragma unroll
      for (int nt = 0; nt < 2; ++nt) {
        f32x4 k0 = __builtin_amdgcn_mfma_f32_16x16x32_bf16(a[r][0], wkf[0][nt], zf, 0, 0, 0);
        kd[r][nt] = __builtin_amdgcn_mfma_f32_16x16x32_bf16(a[r][1], wkf[1][nt], k0, 0, 0, 0);
        f32x4 v0 = __builtin_amdgcn_mfma_f32_16x16x32_bf16(a[r][0], wvf[0][nt], zf, 0, 0, 0);
        vd[r][nt] = __builtin_amdgcn_mfma_f32_16x16x32_bf16(a[r][1], wvf[1][nt], v0, 0, 0, 0);
      }

    // pool 2x2 (x-pairs are adjacent D-rows = adjacent regs; y-pairs = r)
#pragma unroll
    for (int nt = 0; nt < 2; ++nt)
#pragma unroll
      for (int rr = 0; rr < 2; ++rr) {
        const float kp = fmaxf(fmaxf(kd[0][nt][2 * rr], kd[0][nt][2 * rr + 1]),
                               fmaxf(kd[1][nt][2 * rr], kd[1][nt][2 * rr + 1])) + bkv[nt];
        const float vp = fmaxf(fmaxf(vd[0][nt][2 * rr], vd[0][nt][2 * rr + 1]),
                               fmaxf(vd[1][nt][2 * rr], vd[1][nt][2 * rr + 1])) + bvv[nt];
        kvs[wv][quad * 2 + rr][nt * 16 + l15]      = f2bf(kp);
        kvs[wv][quad * 2 + rr][32 + nt * 16 + l15] = f2bf(vp);
      }

    const int gw    = xh * 4 + (t >> 1);
    const int cell  = (n << 6) + (gh << 3) + gw;
    const int kposb = pyc * 16 + (t & 1) * 8;
    if (lane < 32) {
      const s16x8 vv = *(const s16x8*)&kvs[wv][lane >> 2][(lane & 3) * 8];
      *(s16x8*)(kg + ((size_t)(cell << 8) + kposb + (lane >> 2)) * 32 + (lane & 3) * 8) = vv;
    } else {
      const int ch = lane - 32;
      s16x8 vv;
#pragma unroll
      for (int r = 0; r < 8; ++r) vv[r] = (short)kvs[wv][r][32 + ch];
      *(s16x8*)(vt + (size_t)(cell << 13) + ch * 256 + kposb) = vv;
    }
  }
}

// ---------------------------------------------------------------------------
// attn_kernel v4 (r8, proven): grid 512 (2 blocks/cell), 8 waves, 4 M-tiles.
// Swapped S^T = mfma(K,Q); exp/pack/shfl/PV fused per K-slice (low VGPR).
// ---------------------------------------------------------------------------
__global__ __launch_bounds__(512, 2) void attn_kernel(
    const ushort_t* __restrict__ xt, const ushort_t* __restrict__ kg,
    const ushort_t* __restrict__ vt,
    const ushort_t* __restrict__ woq, const float* __restrict__ bq,
    const ushort_t* __restrict__ wou, const float* __restrict__ bo,
    const float* __restrict__ gamma_p, ushort_t* __restrict__ f0)
{
  __shared__ __attribute__((aligned(16))) ushort_t kl[256 * 36];  // K [kpos][32] pad36
  __shared__ __attribute__((aligned(16))) ushort_t vl[32 * 268];  // V^T [ch][256] pad268
  __shared__ __attribute__((aligned(16))) ushort_t un[8][1152];   // per-wave scratch

  const int bid = blockIdx.x;
  const int cell = bid >> 1;
  const int part = bid & 1;
  const int tid = threadIdx.x, lane = tid & 63, wv = tid >> 6;
  const int quad = lane >> 4, l15 = lane & 15;

  const int n  = cell >> 6;
  const int gh = (cell >> 3) & 7;
  const int gw = cell & 7;
  const int y0 = gh * 32, xc0 = gw * 32;

  const ushort_t* xtn = xt + (size_t)n * (65536 * 64);
  ushort_t*       f0n = f0 + (size_t)n * (65536 * 64);
  const ushort_t* kc  = kg + (size_t)(cell << 8) * 32;
  const ushort_t* vc  = vt + (size_t)(cell << 13);

  // ---- stage K and V^T into LDS (one pass, b128 both sides)
  for (int idx = tid; idx < 1024; idx += 512) {
    const int kpos = idx >> 2, cg = idx & 3;
    *(s16x8*)&kl[kpos * 36 + cg * 8] = *(const s16x8*)(kc + kpos * 32 + cg * 8);
  }
  for (int idx = tid; idx < 1024; idx += 512) {
    const int ch = idx >> 5, seg = idx & 31;
    *(s16x8*)&vl[ch * 268 + seg * 8] = *(const s16x8*)(vc + ch * 256 + seg * 8);
  }

  const float gamma = gamma_p[0];

  // Wq B-frags from repacked bf16 (resident; Wo loaded at use)
  s16x8 wqf[2][2];
#pragma unroll
  for (int ks = 0; ks < 2; ++ks)
#pragma unroll
    for (int nt = 0; nt < 2; ++nt)
      wqf[ks][nt] = *(const s16x8*)(woq + (nt * 16 + l15) * 64 + ks * 32 + quad * 8);
  float bqv[2]; bqv[0] = bq[l15]; bqv[1] = bq[16 + l15];
  float bov[4];
#pragma unroll
  for (int nt = 0; nt < 4; ++nt) bov[nt] = bo[nt * 16 + l15];

  __syncthreads();   // K/V staged

  ushort_t* uw = un[wv];
  const f32x4 zf = {0.f, 0.f, 0.f, 0.f};

  // shuffle geometry for P redistribution
  const int src0 = ((quad & 1) << 5) + l15;   // lane (l15, 2*(quad&1))
  const int src1 = src0 + 16;                 // lane (l15, 2*(quad&1)+1)
  const int hsel = quad >> 1;                 // selects hi/lo pk pair

#pragma unroll 1
  for (int it = 0; it < 4; ++it) {
    const int mt = part * 32 + wv * 4 + it;   // 0..63
    const int pbase = mt * 16;

    const int p = pbase + l15;
    const int yy = p >> 5, xx = p & 31;
    const size_t pixg = (size_t)((y0 + yy) * 256 + xc0 + xx);

    // ---- Q-gen from xt
    const s16x8 a0 = *(const s16x8*)(xtn + pixg * 64 + quad * 8);
    const s16x8 a1 = *(const s16x8*)(xtn + pixg * 64 + 32 + quad * 8);
    f32x4 qd0 = zf, qd1 = zf;
    qd0 = __builtin_amdgcn_mfma_f32_16x16x32_bf16(a0, wqf[0][0], qd0, 0, 0, 0);
    qd0 = __builtin_amdgcn_mfma_f32_16x16x32_bf16(a1, wqf[1][0], qd0, 0, 0, 0);
    qd1 = __builtin_amdgcn_mfma_f32_16x16x32_bf16(a0, wqf[0][1], qd1, 0, 0, 0);
    qd1 = __builtin_amdgcn_mfma_f32_16x16x32_bf16(a1, wqf[1][1], qd1, 0, 0, 0);
    // qt phase of union buffer (stride 40)
#pragma unroll
    for (int i = 0; i < 4; ++i) {
      uw[(quad * 4 + i) * 40 + l15]      = f2bf(qd0[i] + bqv[0]);
      uw[(quad * 4 + i) * 40 + 16 + l15] = f2bf(qd1[i] + bqv[1]);
    }
    const s16x8 qa = *(const s16x8*)&uw[l15 * 40 + quad * 8];

    // ---- S^T = K.Q^T (swapped): lane (l15,q) reg i of tile nt holds
    //      S[kpos = 16nt+4q+i][qpix = l15]
    f32x4 St[16];
#pragma unroll
    for (int nt = 0; nt < 16; ++nt) {
      const s16x8 kb = *(const s16x8*)&kl[(nt * 16 + l15) * 36 + quad * 8];
      St[nt] = __builtin_amdgcn_mfma_f32_16x16x32_bf16(kb, qa, zf, 0, 0, 0);
    }

    // ---- global max over 256 kpos for qpix=l15
    float m = St[0][0];
#pragma unroll
    for (int nt = 0; nt < 16; ++nt) {
      m = fmaxf(m, fmaxf(fmaxf(St[nt][0], St[nt][1]), fmaxf(St[nt][2], St[nt][3])));
    }
    m = fmaxf(m, __shfl_xor(m, 16, 64));
    m = fmaxf(m, __shfl_xor(m, 32, 64));

    // ---- fused exp -> cvt_pk -> shfl -> PV MFMA per K-slice (32 kpos).
    float s = 0.f;
    f32x4 O0 = zf, O1 = zf;
#pragma unroll
    for (int kk = 0; kk < 8; ++kk) {
      const float e0 = __expf(St[2 * kk][0] - m);
      const float e1 = __expf(St[2 * kk][1] - m);
      const float e2 = __expf(St[2 * kk][2] - m);
      const float e3 = __expf(St[2 * kk][3] - m);
      const float g0 = __expf(St[2 * kk + 1][0] - m);
      const float g1 = __expf(St[2 * kk + 1][1] - m);
      const float g2 = __expf(St[2 * kk + 1][2] - m);
      const float g3 = __expf(St[2 * kk + 1][3] - m);
      s += ((e0 + e1) + (e2 + e3)) + ((g0 + g1) + (g2 + g3));
      const unsigned int pk0 = cvtpk(e0, e1);   // nt=2kk   kpos {+0,+1}
      const unsigned int pk1 = cvtpk(e2, e3);   // nt=2kk   kpos {+2,+3}
      const unsigned int pk2 = cvtpk(g0, g1);   // nt=2kk+1 kpos {+0,+1}
      const unsigned int pk3 = cvtpk(g2, g3);   // nt=2kk+1 kpos {+2,+3}
      const int A0 = __shfl((int)pk0, src0, 64);
      const int B0 = __shfl((int)pk2, src0, 64);
      const int A1 = __shfl((int)pk1, src0, 64);
      const int B1 = __shfl((int)pk3, src0, 64);
      const int A2 = __shfl((int)pk0, src1, 64);
      const int B2 = __shfl((int)pk2, src1, 64);
      const int A3 = __shfl((int)pk1, src1, 64);
      const int B3 = __shfl((int)pk3, src1, 64);
      union { int w[4]; s16x8 v; } pa;
      pa.w[0] = hsel ? B0 : A0;
      pa.w[1] = hsel ? B1 : A1;
      pa.w[2] = hsel ? B2 : A2;
      pa.w[3] = hsel ? B3 : A3;
      const int kb0 = kk * 32 + quad * 8;
      const s16x8 vb0 = *(const s16x8*)&vl[l15 * 268 + kb0];
      const s16x8 vb1 = *(const s16x8*)&vl[(16 + l15) * 268 + kb0];
      O0 = __builtin_amdgcn_mfma_f32_16x16x32_bf16(pa.v, vb0, O0, 0, 0, 0);
      O1 = __builtin_amdgcn_mfma_f32_16x16x32_bf16(pa.v, vb1, O1, 0, 0, 0);
    }
    s += __shfl_xor(s, 16, 64);
    s += __shfl_xor(s, 32, 64);

    // row sums for this lane's O rows (qpix = 4*quad+i)
    float rv[4];
#pragma unroll
    for (int i = 0; i < 4; ++i) rv[i] = __shfl(s, quad * 4 + i, 64);

    // ---- normalize, C->A (ot phase, stride 40), project Wo
#pragma unroll
    for (int i = 0; i < 4; ++i) {
      const float inv = 1.0f / rv[i];
      uw[(quad * 4 + i) * 40 + l15]      = f2bf(O0[i] * inv);
      uw[(quad * 4 + i) * 40 + 16 + l15] = f2bf(O1[i] * inv);
    }
    const s16x8 oa = *(const s16x8*)&uw[l15 * 40 + quad * 8];
    // ft phase (stride 72): [q][64ch]; Wo B-frags loaded at use (L2-hot)
#pragma unroll
    for (int nt = 0; nt < 4; ++nt) {
      const s16x8 wofn = *(const s16x8*)(wou + (nt * 16 + l15) * 32 + quad * 8);
      f32x4 D = __builtin_amdgcn_mfma_f32_16x16x32_bf16(oa, wofn, zf, 0, 0, 0);
#pragma unroll
      for (int i = 0; i < 4; ++i)
        uw[(quad * 4 + i) * 72 + nt * 16 + l15] = f2bf(gamma * (D[i] + bov[nt]));
    }

    // ---- epilogue: +xt residual, packed cvt, 16B vector stores
    {
      const s16x8 fv0 = *(const s16x8*)&uw[l15 * 72 + quad * 16];
      const s16x8 fv1 = *(const s16x8*)&uw[l15 * 72 + quad * 16 + 8];
      const s16x8 xv0 = *(const s16x8*)(xtn + pixg * 64 + quad * 16);
      const s16x8 xv1 = *(const s16x8*)(xtn + pixg * 64 + quad * 16 + 8);
      union { unsigned int w[4]; s16x8 v; } r0, r1;
#pragma unroll
      for (int k = 0; k < 4; ++k) {
        const float p0 = bf2f((unsigned short)fv0[2 * k])     + bf2f((unsigned short)xv0[2 * k]);
        const float p1 = bf2f((unsigned short)fv0[2 * k + 1]) + bf2f((unsigned short)xv0[2 * k + 1]);
        const float p2 = bf2f((unsigned short)fv1[2 * k])     + bf2f((unsigned short)xv1[2 * k]);
        const float p3 = bf2f((unsigned short)fv1[2 * k + 1]) + bf2f((unsigned short)xv1[2 * k + 1]);
        r0.w[k] = cvtpk(p0, p1);
        r1.w[k] = cvtpk(p2, p3);
      }
      *(s16x8*)(f0n + pixg * 64 + quad * 16)     = r0.v;
      *(s16x8*)(f0n + pixg * 64 + quad * 16 + 8) = r1.v;
    }
  }
}

// ---------------------------------------------------------------------------
// conv3x3 + ReLU via bf16 MFMA implicit GEMM.
// Round-10: batched-issue staging + LDS-transpose vector-store epilogue.
// ---------------------------------------------------------------------------
template <int NCHUNK>
__global__ __launch_bounds__(256) void conv3_kernel(
    const ushort_t* __restrict__ s0, const ushort_t* __restrict__ s1,
    const ushort_t* __restrict__ s2, const ushort_t* __restrict__ wc,
    const float* __restrict__ bias, ushort_t* __restrict__ outp)
{
  __shared__ __attribute__((aligned(16))) ushort_t tile[612 * 40];

  const int bid = blockIdx.x;
  const int n = bid >> 7;
  const int t = bid & 127;
  const int ty0 = (t >> 3) * 16;
  const int tx0 = (t & 7) * 32;
  const int tid = threadIdx.x, lane = tid & 63, wv = tid >> 6;
  const int quad = lane >> 4, l15 = lane & 15;
  constexpr int Kg = NCHUNK * 4;

  const ushort_t* s0n = s0 + (size_t)n * (65536 * 64);
  const ushort_t* s1n = s1 + (size_t)n * (65536 * 32);
  const ushort_t* s2n = s2 + (size_t)n * (65536 * 32);

  // staging geometry: element idx = tid + 256k -> pix = (tid>>2)+64k, cg = tid&3
  const int cg = tid & 3;
  int offs[10];
#pragma unroll
  for (int k = 0; k < 10; ++k) {
    const int pix = (tid >> 2) + 64 * k;
    int o = -1;
    if (pix < 612) {
      const int lr = pix / 34, lc = pix - lr * 34;
      const int gy = ty0 - 1 + lr, gx = tx0 - 1 + lc;
      if ((unsigned)gy < 256u && (unsigned)gx < 256u) o = gy * 256 + gx;
    }
    offs[k] = o;
  }

  const f32x4 zf = {0.f, 0.f, 0.f, 0.f};
  f32x4 acc[4][2][2];
#pragma unroll
  for (int r = 0; r < 4; ++r)
#pragma unroll
    for (int h = 0; h < 2; ++h) { acc[r][h][0] = zf; acc[r][h][1] = zf; }

#pragma unroll
  for (int ch = 0; ch < NCHUNK; ++ch) {
    const ushort_t* src; int cstr, cbase;
    if (ch < 2)       { src = s0n; cstr = 64; cbase = ch * 32; }
    else if (ch == 2) { src = s1n; cstr = 32; cbase = 0; }
    else              { src = s2n; cstr = 32; cbase = 0; }

    // batched global loads (independent -> one exposed latency, not ~10)
    s16x8 R[10];
#pragma unroll
    for (int k = 0; k < 10; ++k) {
      const int pix = (tid >> 2) + 64 * k;
      if (pix < 612) {
        s16x8 v = {0, 0, 0, 0, 0, 0, 0, 0};
        if (offs[k] >= 0)
          v = *(const s16x8*)(src + (size_t)offs[k] * cstr + cbase + cg * 8);
        R[k] = v;
      }
    }
    __syncthreads();
#pragma unroll
    for (int k = 0; k < 10; ++k) {
      const int pix = (tid >> 2) + 64 * k;
      if (pix < 612) *(s16x8*)&tile[pix * 40 + cg * 8] = R[k];
    }
    __syncthreads();

#pragma unroll
    for (int tap = 0; tap < 9; ++tap) {
      const int ky = tap / 3, kx = tap - ky * 3;
      const ushort_t* wb = wc + ((size_t)(tap * Kg + ch * 4 + quad) * 32 + l15) * 8;
      const s16x8 b0 = *(const s16x8*)wb;
      const s16x8 b1 = *(const s16x8*)(wb + 128);
#pragma unroll
      for (int r = 0; r < 4; ++r) {
        const int lr = 4 * wv + r + ky;
#pragma unroll
        for (int h = 0; h < 2; ++h) {
          const int lc = h * 16 + l15 + kx;
          const s16x8 a = *(const s16x8*)&tile[(lr * 34 + lc) * 40 + quad * 8];
          acc[r][h][0] = __builtin_amdgcn_mfma_f32_16x16x32_bf16(a, b0, acc[r][h][0], 0, 0, 0);
          acc[r][h][1] = __builtin_amdgcn_mfma_f32_16x16x32_bf16(a, b1, acc[r][h][1], 0, 0, 0);
        }
      }
    }
  }

  // ---- epilogue: acc -> LDS [512 px][stride 40] -> 8x b128 coalesced stores
  __syncthreads();   // all waves done reading tile
  const float bv0 = bias[l15], bv1 = bias[16 + l15];
#pragma unroll
  for (int r = 0; r < 4; ++r)
#pragma unroll
    for (int h = 0; h < 2; ++h)
#pragma unroll
      for (int i = 0; i < 4; ++i) {
        const int lpix = (4 * wv + r) * 32 + h * 16 + quad * 4 + i;
        tile[lpix * 40 + l15]      = f2bf(fmaxf(acc[r][h][0][i] + bv0, 0.f));
        tile[lpix * 40 + 16 + l15] = f2bf(fmaxf(acc[r][h][1][i] + bv1, 0.f));
      }
  __syncthreads();
  ushort_t* on = outp + (size_t)n * (65536 * 32);
#pragma unroll
  for (int k = 0; k < 8; ++k) {
    const int idx = tid + (k << 8);
    const int lpix = idx >> 2, cgg = idx & 3;
    const int gy = ty0 + (lpix >> 5), gx = tx0 + (lpix & 31);
    *(s16x8*)(on + (size_t)(gy * 256 + gx) * 32 + cgg * 8) =
        *(const s16x8*)&tile[lpix * 40 + cgg * 8];
  }
}

// ---------------------------------------------------------------------------
// fuse: out = cat(f0..f3)[160] x Wf^T + bf + x (unchanged).
// ---------------------------------------------------------------------------
__global__ __launch_bounds__(256) void fuse_kernel(
    const ushort_t* __restrict__ f0, const ushort_t* __restrict__ f1,
    const ushort_t* __restrict__ f2, const ushort_t* __restrict__ f3,
    const float* __restrict__ x, const ushort_t* __restrict__ wff,
    const float* __restrict__ bfv, float* __restrict__ out)
{
  __shared__ float tr[4][64 * 17];

  const int tid = threadIdx.x, lane = tid & 63, wv = tid >> 6;
  const int quad = lane >> 4, l15 = lane & 15;

  s16x8 wf[5][4];
#pragma unroll
  for (int ks = 0; ks < 5; ++ks)
#pragma unroll
    for (int nt = 0; nt < 4; ++nt)
      wf[ks][nt] = *(const s16x8*)(wff + ((size_t)((ks * 4 + quad) * 64) + nt * 16 + l15) * 8);
  float bb[4];
#pragma unroll
  for (int nt = 0; nt < 4; ++nt) bb[nt] = bfv[nt * 16 + l15];

  const int wt = blockIdx.x * 4 + wv;
  const f32x4 zf = {0.f, 0.f, 0.f, 0.f};
  float* trw = tr[wv];

  for (int mt = 0; mt < 4; ++mt) {
    const int p0 = wt * 64 + mt * 16;
    const size_t pA = (size_t)(p0 + l15);
    const s16x8 a0 = *(const s16x8*)(f0 + pA * 64 + quad * 8);
    const s16x8 a1 = *(const s16x8*)(f0 + pA * 64 + 32 + quad * 8);
    const s16x8 a2 = *(const s16x8*)(f1 + pA * 32 + quad * 8);
    const s16x8 a3 = *(const s16x8*)(f2 + pA * 32 + quad * 8);
    const s16x8 a4 = *(const s16x8*)(f3 + pA * 32 + quad * 8);

    f32x4 acc[4];
#pragma unroll
    for (int nt = 0; nt < 4; ++nt) {
      f32x4 d = zf;
      d = __builtin_amdgcn_mfma_f32_16x16x32_bf16(a0, wf[0][nt], d, 0, 0, 0);
      d = __builtin_amdgcn_mfma_f32_16x16x32_bf16(a1, wf[1][nt], d, 0, 0, 0);
      d = __builtin_amdgcn_mfma_f32_16x16x32_bf16(a2, wf[2][nt], d, 0, 0, 0);
      d = __builtin_amdgcn_mfma_f32_16x16x32_bf16(a3, wf[3][nt], d, 0, 0, 0);
      d = __builtin_amdgcn_mfma_f32_16x16x32_bf16(a4, wf[4][nt], d, 0, 0, 0);
      acc[nt] = d;
    }

#pragma unroll
    for (int nt = 0; nt < 4; ++nt)
#pragma unroll
      for (int i = 0; i < 4; ++i)
        trw[(nt * 16 + l15) * 17 + quad * 4 + i] = acc[nt][i] + bb[nt];

    const int n = p0 >> 16;
    const int pix0 = p0 & 65535;
    const float* xb = x + (size_t)n * (64 * 65536);
    float* ob = out + (size_t)n * (64 * 65536);
#pragma unroll
    for (int og = 0; og < 16; ++og) {
      const int o = og * 4 + quad;
      const float v = trw[o * 17 + l15];
      const size_t g = (size_t)o * 65536 + pix0 + l15;
      ob[g] = v + xb[g];
    }
  }
}

// ---------------------------------------------------------------------------
extern "C" void kernel_launch(void* const* d_in, const int* in_sizes, int n_in,
                              void* d_out, int out_size, void* d_ws, size_t ws_size,
                              hipStream_t stream)
{
  const float* x     = (const float*)d_in[0];
  const float* Wq    = (const float*)d_in[1];
  const float* bq    = (const float*)d_in[2];
  const float* Wk    = (const float*)d_in[3];
  const float* bk    = (const float*)d_in[4];
  const float* Wv    = (const float*)d_in[5];
  const float* bv    = (const float*)d_in[6];
  const float* Wo    = (const float*)d_in[7];
  const float* bo    = (const float*)d_in[8];
  const float* gamma = (const float*)d_in[9];
  const float* W1    = (const float*)d_in[10];
  const float* b1    = (const float*)d_in[11];
  const float* W2    = (const float*)d_in[12];
  const float* b2    = (const float*)d_in[13];
  const float* W3    = (const float*)d_in[14];
  const float* b3    = (const float*)d_in[15];
  const float* Wf    = (const float*)d_in[16];
  const float* bf    = (const float*)d_in[17];

  float* out = (float*)d_out;
  ushort_t* wsu = (ushort_t*)d_ws;

  // bf16 feature buffers, pixel-major [n][y][x][c]
  ushort_t* f0 = wsu;                       // 16,777,216
  ushort_t* f1 = wsu + 16777216;            //  8,388,608
  ushort_t* f2 = wsu + 25165824;            //  8,388,608
  ushort_t* f3 = wsu + 33554432;            //  8,388,608
  // xt overlays f1+f2 (dead before conv1 writes f1);
  // kg/vt overlay f3 (dead before conv3 writes f3)
  ushort_t* xtb = wsu + 16777216;           // 16,777,216
  ushort_t* kgb = wsu + 33554432;           //  2,097,152
  ushort_t* vtb = wsu + 35651584;           //  2,097,152
  ushort_t* wc1 = wsu + 41943040;           // 18432
  ushort_t* wc2 = wc1 + 18432;              // 27648
  ushort_t* wc3 = wc2 + 27648;              // 36864
  ushort_t* wff = wc3 + 36864;              // 10240
  ushort_t* woq = wff + 10240;              // 2048
  ushort_t* wou = woq + 2048;               // 2048

  repack_kernel<<<144, 256, 0, stream>>>(W1, W2, W3, Wf, Wq, Wo,
                                         wc1, wc2, wc3, wff, woq, wou);
  kvx_kernel<<<1024, 256, 0, stream>>>(x, Wk, bk, Wv, bv, xtb, kgb, vtb);
  attn_kernel<<<512, 512, 0, stream>>>(xtb, kgb, vtb, woq, bq, wou, bo, gamma, f0);
  conv3_kernel<2><<<512, 256, 0, stream>>>(f0, f1, f2, wc1, b1, f1);
  conv3_kernel<3><<<512, 256, 0, stream>>>(f0, f1, f2, wc2, b2, f2);
  conv3_kernel<4><<<512, 256, 0, stream>>>(f0, f1, f2, wc3, b3, f3);
  fuse_kernel<<<1024, 256, 0, stream>>>(f0, f1, f2, f3, x, wff, bf, out);
}

// Round 6
// 312.145 us; speedup vs baseline: 1.1641x; 1.0142x over previous
//
#include <hip/hip_runtime.h>

// ============================================================================
// RegionNonLocalEnhancedDenseBlock on MI355X (gfx950) — Round 11
//  - attn_kernel v6: two-pass S (recompute) kills the register spill.
//    r10 evidence: VGPR=128 (at cap), WRITE_SIZE 45MB vs 33.5MB logical
//    = ~11.5MB scratch writes/dispatch. St[16] (64 f32) live across the
//    max-reduction was the pressure. Pass A: 16 S MFMAs feeding only the
//    running max (St transient). Pass B: recompute S per 2-tile slice
//    inside the fused exp/cvt_pk/shfl/PV loop (<=2 St live). Bit-identical
//    numerics; peak regs ~90 -> no spill.
//  - kvx (r6), conv3 (r10), fuse, repack unchanged.
// ============================================================================

typedef short s16x8 __attribute__((ext_vector_type(8)));
typedef float f32x4 __attribute__((ext_vector_type(4)));
typedef unsigned short ushort_t;

__device__ __forceinline__ unsigned short f2bf(float f) {
  union { float f; unsigned int u; } v; v.f = f;
  unsigned int r = v.u + 0x7fffu + ((v.u >> 16) & 1u);  // RNE
  return (unsigned short)(r >> 16);
}
__device__ __forceinline__ float bf2f(unsigned short h) {
  union { unsigned int u; float f; } v; v.u = ((unsigned int)h) << 16;
  return v.f;
}
// packed f32x2 -> bf16x2 (RNE), lo = a, hi = b
__device__ __forceinline__ unsigned int cvtpk(float a, float b) {
  unsigned int r;
  asm("v_cvt_pk_bf16_f32 %0, %1, %2" : "=v"(r) : "v"(a), "v"(b));
  return r;
}

// ---------------------------------------------------------------------------
// Repack conv/fuse weights -> bf16 MFMA B-frag order; Wq/Wo -> linear bf16.
// ---------------------------------------------------------------------------
__global__ void repack_kernel(const float* __restrict__ W1, const float* __restrict__ W2,
                              const float* __restrict__ W3, const float* __restrict__ Wf,
                              const float* __restrict__ Wq, const float* __restrict__ Wo,
                              ushort_t* __restrict__ wc1, ushort_t* __restrict__ wc2,
                              ushort_t* __restrict__ wc3, ushort_t* __restrict__ wff,
                              ushort_t* __restrict__ woq, ushort_t* __restrict__ wou)
{
  const int i = blockIdx.x * 256 + threadIdx.x;
  if (i < 18432) {  // W1 [32][64][3][3], Kg=8
    int j = i & 7, o = (i >> 3) & 31, r = i >> 8, tap = r >> 3, kg = r & 7;
    wc1[i] = f2bf(W1[o * 576 + (kg * 8 + j) * 9 + tap]);
  }
  if (i < 27648) {  // W2 [32][96][3][3], Kg=12
    int j = i & 7, o = (i >> 3) & 31, r = i >> 8, tap = r / 12, kg = r % 12;
    wc2[i] = f2bf(W2[o * 864 + (kg * 8 + j) * 9 + tap]);
  }
  if (i < 36864) {  // W3 [32][128][3][3], Kg=16
    int j = i & 7, o = (i >> 3) & 31, r = i >> 8, tap = r >> 4, kg = r & 15;
    wc3[i] = f2bf(W3[o * 1152 + (kg * 8 + j) * 9 + tap]);
  }
  if (i < 10240) {  // Wf [64][160], Kg=20
    int j = i & 7, o = (i >> 3) & 63, kg = i >> 9;
    wff[i] = f2bf(Wf[o * 160 + kg * 8 + j]);
  }
  if (i < 2048) {   // Wq [32][64] linear, Wo [64][32] linear
    woq[i] = f2bf(Wq[i]);
    wou[i] = f2bf(Wo[i]);
  }
}

// ---------------------------------------------------------------------------
// kvx_kernel: grid 1024 = n(4) x pooled_row(128) x x_half(2). (unchanged r6)
// ---------------------------------------------------------------------------
__global__ __launch_bounds__(256, 4) void kvx_kernel(
    const float* __restrict__ x,
    const float* __restrict__ Wk, const float* __restrict__ bk,
    const float* __restrict__ Wv, const float* __restrict__ bv,
    ushort_t* __restrict__ xt, ushort_t* __restrict__ kg, ushort_t* __restrict__ vt)
{
  __shared__ __attribute__((aligned(16))) ushort_t lds[64 * 258];  // [c][258]
  __shared__ ushort_t kvs[4][8][64];  // [wave][kpos_local][K 0..31 | V 32..63]

  const int bid = blockIdx.x;
  const int n   = bid >> 8;
  const int rem = bid & 255;
  const int pr  = rem >> 1;            // pooled row 0..127
  const int xh  = rem & 1;             // x half
  const int tid = threadIdx.x, lane = tid & 63, wv = tid >> 6;
  const int quad = lane >> 4, l15 = lane & 15;

  const int y0 = pr * 2;
  const int x0 = xh * 128;
  const int gh = pr >> 4, pyc = pr & 15;

  const float* xblk = x + (size_t)n * (64 * 65536) + (size_t)(y0 * 256 + x0);
  ushort_t*    xtn  = xt + (size_t)n * (65536 * 64);

  // ---- phase 1: x -> LDS (coalesced 512B runs per instruction)
#pragma unroll 4
  for (int i = 0; i < 16; ++i) {
    const int idx = (i << 8) + tid;          // 0..4095 float4s
    const int c  = idx >> 6;                 // 64 float4 per channel
    const int r  = (idx >> 5) & 1;
    const int sg = idx & 31;
    const f32x4 v = *(const f32x4*)(xblk + (size_t)c * 65536 + r * 256 + sg * 4);
    const unsigned int lo = (unsigned int)f2bf(v[0]) | ((unsigned int)f2bf(v[1]) << 16);
    const unsigned int hi = (unsigned int)f2bf(v[2]) | ((unsigned int)f2bf(v[3]) << 16);
    const int base = c * 258 + (r << 7) + (sg << 2);   // u16 index, 4B aligned
    *(unsigned int*)&lds[base]     = lo;
    *(unsigned int*)&lds[base + 2] = hi;
  }

  // ---- K/V weight B-frags (L2-resident, overlaps phase-1 drain)
  s16x8 wkf[2][2], wvf[2][2];
#pragma unroll
  for (int ks = 0; ks < 2; ++ks)
#pragma unroll
    for (int nt = 0; nt < 2; ++nt) {
      const int off = (nt * 16 + l15) * 64 + ks * 32 + quad * 8;
      s16x8 tk, tv;
#pragma unroll
      for (int j = 0; j < 8; ++j) {
        tk[j] = (short)f2bf(Wk[off + j]);
        tv[j] = (short)f2bf(Wv[off + j]);
      }
      wkf[ks][nt] = tk; wvf[ks][nt] = tv;
    }
  float bkv[2], bvv[2];
#pragma unroll
  for (int nt = 0; nt < 2; ++nt) {
    bkv[nt] = bk[nt * 16 + l15];
    bvv[nt] = bv[nt * 16 + l15];
  }

  __syncthreads();

  // ---- phase 2a: xt stores — lane = (pixel_octet, ch_octet); 1KB contiguous
  {
    const int g  = lane & 7;        // channel octet
    const int pa = lane >> 3;       // pixel within octet run
#pragma unroll
    for (int s = 0; s < 8; ++s) {
      const int p = (wv << 6) + (s << 3) + pa;        // 0..255 local pixel
      s16x8 v;
#pragma unroll
      for (int j = 0; j < 8; ++j) v[j] = (short)lds[(g * 8 + j) * 258 + p];
      const int P = (y0 + (p >> 7)) * 256 + x0 + (p & 127);
      *(s16x8*)(xtn + (size_t)P * 64 + g * 8) = v;
    }
  }

  // ---- phase 2b: K/V — 2 x-tiles (16px) per wave, both rows, pool 2x2
  const f32x4 zf = {0.f, 0.f, 0.f, 0.f};
#pragma unroll
  for (int tt = 0; tt < 2; ++tt) {
    const int t   = wv * 2 + tt;          // x-tile 0..7 (local)
    const int px0 = t * 16 + l15;

    s16x8 a[2][2];                        // [row][ks]
#pragma unroll
    for (int r = 0; r < 2; ++r)
#pragma unroll
      for (int ks = 0; ks < 2; ++ks) {
        s16x8 v;
#pragma unroll
        for (int j = 0; j < 8; ++j)
          v[j] = (short)lds[(ks * 32 + quad * 8 + j) * 258 + (r << 7) + px0];
        a[r][ks] = v;
      }

    f32x4 kd[2][2], vd[2][2];             // [row][nt]
#pragma unroll
    for (int r = 0; r < 2; ++r)
#pragma unroll
      for (int nt = 0; nt < 2; ++nt) {
        f32x4 k0 = __builtin_amdgcn_mfma_f32_16x16x32_bf16(a[r][0], wkf[0][nt], zf, 0, 0, 0);
        kd[r][nt] = __builtin_amdgcn_mfma_f32_16x16x32_bf16(a[r][1], wkf[1][nt], k0, 0, 0, 0);
        f32x4 v0 = __builtin_amdgcn_mfma_f32_16x16x32_bf16(a[r][0], wvf[0][nt], zf, 0, 0, 0);
        vd[r][nt] = __builtin_amdgcn_mfma_f32_16x16x32_bf16(a[r][1], wvf[1][nt], v0, 0, 0, 0);
      }

    // pool 2x2 (x-pairs are adjacent D-rows = adjacent regs; y-pairs = r)
#pragma unroll
    for (int nt = 0; nt < 2; ++nt)
#pragma unroll
      for (int rr = 0; rr < 2; ++rr) {
        const float kp = fmaxf(fmaxf(kd[0][nt][2 * rr], kd[0][nt][2 * rr + 1]),
                               fmaxf(kd[1][nt][2 * rr], kd[1][nt][2 * rr + 1])) + bkv[nt];
        const float vp = fmaxf(fmaxf(vd[0][nt][2 * rr], vd[0][nt][2 * rr + 1]),
                               fmaxf(vd[1][nt][2 * rr], vd[1][nt][2 * rr + 1])) + bvv[nt];
        kvs[wv][quad * 2 + rr][nt * 16 + l15]      = f2bf(kp);
        kvs[wv][quad * 2 + rr][32 + nt * 16 + l15] = f2bf(vp);
      }

    const int gw    = xh * 4 + (t >> 1);
    const int cell  = (n << 6) + (gh << 3) + gw;
    const int kposb = pyc * 16 + (t & 1) * 8;
    if (lane < 32) {
      const s16x8 vv = *(const s16x8*)&kvs[wv][lane >> 2][(lane & 3) * 8];
      *(s16x8*)(kg + ((size_t)(cell << 8) + kposb + (lane >> 2)) * 32 + (lane & 3) * 8) = vv;
    } else {
      const int ch = lane - 32;
      s16x8 vv;
#pragma unroll
      for (int r = 0; r < 8; ++r) vv[r] = (short)kvs[wv][r][32 + ch];
      *(s16x8*)(vt + (size_t)(cell << 13) + ch * 256 + kposb) = vv;
    }
  }
}

// ---------------------------------------------------------------------------
// attn_kernel v6: grid 512 (2 blocks/cell), 8 waves, 4 M-tiles/wave.
// Two-pass S (pass A: max only; pass B: recompute fused with exp/shfl/PV).
// ---------------------------------------------------------------------------
__global__ __launch_bounds__(512, 2) void attn_kernel(
    const ushort_t* __restrict__ xt, const ushort_t* __restrict__ kg,
    const ushort_t* __restrict__ vt,
    const ushort_t* __restrict__ woq, const float* __restrict__ bq,
    const ushort_t* __restrict__ wou, const float* __restrict__ bo,
    const float* __restrict__ gamma_p, ushort_t* __restrict__ f0)
{
  __shared__ __attribute__((aligned(16))) ushort_t kl[256 * 36];  // K [kpos][32] pad36
  __shared__ __attribute__((aligned(16))) ushort_t vl[32 * 268];  // V^T [ch][256] pad268
  __shared__ __attribute__((aligned(16))) ushort_t un[8][1152];   // per-wave scratch

  const int bid = blockIdx.x;
  const int cell = bid >> 1;
  const int part = bid & 1;
  const int tid = threadIdx.x, lane = tid & 63, wv = tid >> 6;
  const int quad = lane >> 4, l15 = lane & 15;

  const int n  = cell >> 6;
  const int gh = (cell >> 3) & 7;
  const int gw = cell & 7;
  const int y0 = gh * 32, xc0 = gw * 32;

  const ushort_t* xtn = xt + (size_t)n * (65536 * 64);
  ushort_t*       f0n = f0 + (size_t)n * (65536 * 64);
  const ushort_t* kc  = kg + (size_t)(cell << 8) * 32;
  const ushort_t* vc  = vt + (size_t)(cell << 13);

  // ---- stage K and V^T into LDS (one pass, b128 both sides)
  for (int idx = tid; idx < 1024; idx += 512) {
    const int kpos = idx >> 2, cg = idx & 3;
    *(s16x8*)&kl[kpos * 36 + cg * 8] = *(const s16x8*)(kc + kpos * 32 + cg * 8);
  }
  for (int idx = tid; idx < 1024; idx += 512) {
    const int ch = idx >> 5, seg = idx & 31;
    *(s16x8*)&vl[ch * 268 + seg * 8] = *(const s16x8*)(vc + ch * 256 + seg * 8);
  }

  const float gamma = gamma_p[0];

  // Wq B-frags from repacked bf16 (resident; Wo loaded at use)
  s16x8 wqf[2][2];
#pragma unroll
  for (int ks = 0; ks < 2; ++ks)
#pragma unroll
    for (int nt = 0; nt < 2; ++nt)
      wqf[ks][nt] = *(const s16x8*)(woq + (nt * 16 + l15) * 64 + ks * 32 + quad * 8);
  float bqv[2]; bqv[0] = bq[l15]; bqv[1] = bq[16 + l15];
  float bov[4];
#pragma unroll
  for (int nt = 0; nt < 4; ++nt) bov[nt] = bo[nt * 16 + l15];

  __syncthreads();   // K/V staged

  ushort_t* uw = un[wv];
  const f32x4 zf = {0.f, 0.f, 0.f, 0.f};

  // shuffle geometry for P redistribution
  const int src0 = ((quad & 1) << 5) + l15;   // lane (l15, 2*(quad&1))
  const int src1 = src0 + 16;                 // lane (l15, 2*(quad&1)+1)
  const int hsel = quad >> 1;                 // selects hi/lo pk pair

#pragma unroll 1
  for (int it = 0; it < 4; ++it) {
    const int mt = part * 32 + wv * 4 + it;   // 0..63
    const int pbase = mt * 16;

    const int p = pbase + l15;
    const int yy = p >> 5, xx = p & 31;
    const size_t pixg = (size_t)((y0 + yy) * 256 + xc0 + xx);

    // ---- Q-gen from xt
    const s16x8 a0 = *(const s16x8*)(xtn + pixg * 64 + quad * 8);
    const s16x8 a1 = *(const s16x8*)(xtn + pixg * 64 + 32 + quad * 8);
    f32x4 qd0 = zf, qd1 = zf;
    qd0 = __builtin_amdgcn_mfma_f32_16x16x32_bf16(a0, wqf[0][0], qd0, 0, 0, 0);
    qd0 = __builtin_amdgcn_mfma_f32_16x16x32_bf16(a1, wqf[1][0], qd0, 0, 0, 0);
    qd1 = __builtin_amdgcn_mfma_f32_16x16x32_bf16(a0, wqf[0][1], qd1, 0, 0, 0);
    qd1 = __builtin_amdgcn_mfma_f32_16x16x32_bf16(a1, wqf[1][1], qd1, 0, 0, 0);
    // qt phase of union buffer (stride 40)
#pragma unroll
    for (int i = 0; i < 4; ++i) {
      uw[(quad * 4 + i) * 40 + l15]      = f2bf(qd0[i] + bqv[0]);
      uw[(quad * 4 + i) * 40 + 16 + l15] = f2bf(qd1[i] + bqv[1]);
    }
    const s16x8 qa = *(const s16x8*)&uw[l15 * 40 + quad * 8];

    // ---- pass A: S^T = K.Q^T, max only (St transient -> no big live range)
    float m;
    {
      const s16x8 kb0 = *(const s16x8*)&kl[(0 * 16 + l15) * 36 + quad * 8];
      const f32x4 S0 = __builtin_amdgcn_mfma_f32_16x16x32_bf16(kb0, qa, zf, 0, 0, 0);
      m = fmaxf(fmaxf(S0[0], S0[1]), fmaxf(S0[2], S0[3]));
    }
#pragma unroll
    for (int nt = 1; nt < 16; ++nt) {
      const s16x8 kb = *(const s16x8*)&kl[(nt * 16 + l15) * 36 + quad * 8];
      const f32x4 S = __builtin_amdgcn_mfma_f32_16x16x32_bf16(kb, qa, zf, 0, 0, 0);
      m = fmaxf(m, fmaxf(fmaxf(S[0], S[1]), fmaxf(S[2], S[3])));
    }
    m = fmaxf(m, __shfl_xor(m, 16, 64));
    m = fmaxf(m, __shfl_xor(m, 32, 64));

    // ---- pass B: recompute S per 2-tile slice, fused exp/cvt_pk/shfl/PV
    float s = 0.f;
    f32x4 O0 = zf, O1 = zf;
#pragma unroll
    for (int kk = 0; kk < 8; ++kk) {
      const s16x8 kb0 = *(const s16x8*)&kl[((2 * kk) * 16 + l15) * 36 + quad * 8];
      const s16x8 kb1 = *(const s16x8*)&kl[((2 * kk + 1) * 16 + l15) * 36 + quad * 8];
      const f32x4 Sa = __builtin_amdgcn_mfma_f32_16x16x32_bf16(kb0, qa, zf, 0, 0, 0);
      const f32x4 Sb = __builtin_amdgcn_mfma_f32_16x16x32_bf16(kb1, qa, zf, 0, 0, 0);
      const float e0 = __expf(Sa[0] - m);
      const float e1 = __expf(Sa[1] - m);
      const float e2 = __expf(Sa[2] - m);
      const float e3 = __expf(Sa[3] - m);
      const float g0 = __expf(Sb[0] - m);
      const float g1 = __expf(Sb[1] - m);
      const float g2 = __expf(Sb[2] - m);
      const float g3 = __expf(Sb[3] - m);
      s += ((e0 + e1) + (e2 + e3)) + ((g0 + g1) + (g2 + g3));
      const unsigned int pk0 = cvtpk(e0, e1);   // nt=2kk   kpos {+0,+1}
      const unsigned int pk1 = cvtpk(e2, e3);   // nt=2kk   kpos {+2,+3}
      const unsigned int pk2 = cvtpk(g0, g1);   // nt=2kk+1 kpos {+0,+1}
      const unsigned int pk3 = cvtpk(g2, g3);   // nt=2kk+1 kpos {+2,+3}
      const int A0 = __shfl((int)pk0, src0, 64);
      const int B0 = __shfl((int)pk2, src0, 64);
      const int A1 = __shfl((int)pk1, src0, 64);
      const int B1 = __shfl((int)pk3, src0, 64);
      const int A2 = __shfl((int)pk0, src1, 64);
      const int B2 = __shfl((int)pk2, src1, 64);
      const int A3 = __shfl((int)pk1, src1, 64);
      const int B3 = __shfl((int)pk3, src1, 64);
      union { int w[4]; s16x8 v; } pa;
      pa.w[0] = hsel ? B0 : A0;
      pa.w[1] = hsel ? B1 : A1;
      pa.w[2] = hsel ? B2 : A2;
      pa.w[3] = hsel ? B3 : A3;
      const int kb0i = kk * 32 + quad * 8;
      const s16x8 vb0 = *(const s16x8*)&vl[l15 * 268 + kb0i];
      const s16x8 vb1 = *(const s16x8*)&vl[(16 + l15) * 268 + kb0i];
      O0 = __builtin_amdgcn_mfma_f32_16x16x32_bf16(pa.v, vb0, O0, 0, 0, 0);
      O1 = __builtin_amdgcn_mfma_f32_16x16x32_bf16(pa.v, vb1, O1, 0, 0, 0);
    }
    s += __shfl_xor(s, 16, 64);
    s += __shfl_xor(s, 32, 64);

    // row sums for this lane's O rows (qpix = 4*quad+i)
    float rv[4];
#pragma unroll
    for (int i = 0; i < 4; ++i) rv[i] = __shfl(s, quad * 4 + i, 64);

    // ---- normalize, C->A (ot phase, stride 40), project Wo
#pragma unroll
    for (int i = 0; i < 4; ++i) {
      const float inv = 1.0f / rv[i];
      uw[(quad * 4 + i) * 40 + l15]      = f2bf(O0[i] * inv);
      uw[(quad * 4 + i) * 40 + 16 + l15] = f2bf(O1[i] * inv);
    }
    const s16x8 oa = *(const s16x8*)&uw[l15 * 40 + quad * 8];
    // ft phase (stride 72): [q][64ch]; Wo B-frags loaded at use (L2-hot)
#pragma unroll
    for (int nt = 0; nt < 4; ++nt) {
      const s16x8 wofn = *(const s16x8*)(wou + (nt * 16 + l15) * 32 + quad * 8);
      f32x4 D = __builtin_amdgcn_mfma_f32_16x16x32_bf16(oa, wofn, zf, 0, 0, 0);
#pragma unroll
      for (int i = 0; i < 4; ++i)
        uw[(quad * 4 + i) * 72 + nt * 16 + l15] = f2bf(gamma * (D[i] + bov[nt]));
    }

    // ---- epilogue: +xt residual, packed cvt, 16B vector stores
    {
      const s16x8 fv0 = *(const s16x8*)&uw[l15 * 72 + quad * 16];
      const s16x8 fv1 = *(const s16x8*)&uw[l15 * 72 + quad * 16 + 8];
      const s16x8 xv0 = *(const s16x8*)(xtn + pixg * 64 + quad * 16);
      const s16x8 xv1 = *(const s16x8*)(xtn + pixg * 64 + quad * 16 + 8);
      union { unsigned int w[4]; s16x8 v; } r0, r1;
#pragma unroll
      for (int k = 0; k < 4; ++k) {
        const float p0 = bf2f((unsigned short)fv0[2 * k])     + bf2f((unsigned short)xv0[2 * k]);
        const float p1 = bf2f((unsigned short)fv0[2 * k + 1]) + bf2f((unsigned short)xv0[2 * k + 1]);
        const float p2 = bf2f((unsigned short)fv1[2 * k])     + bf2f((unsigned short)xv1[2 * k]);
        const float p3 = bf2f((unsigned short)fv1[2 * k + 1]) + bf2f((unsigned short)xv1[2 * k + 1]);
        r0.w[k] = cvtpk(p0, p1);
        r1.w[k] = cvtpk(p2, p3);
      }
      *(s16x8*)(f0n + pixg * 64 + quad * 16)     = r0.v;
      *(s16x8*)(f0n + pixg * 64 + quad * 16 + 8) = r1.v;
    }
  }
}

// ---------------------------------------------------------------------------
// conv3x3 + ReLU via bf16 MFMA implicit GEMM (r10: batched staging +
// LDS-transpose vector-store epilogue).
// ---------------------------------------------------------------------------
template <int NCHUNK>
__global__ __launch_bounds__(256) void conv3_kernel(
    const ushort_t* __restrict__ s0, const ushort_t* __restrict__ s1,
    const ushort_t* __restrict__ s2, const ushort_t* __restrict__ wc,
    const float* __restrict__ bias, ushort_t* __restrict__ outp)
{
  __shared__ __attribute__((aligned(16))) ushort_t tile[612 * 40];

  const int bid = blockIdx.x;
  const int n = bid >> 7;
  const int t = bid & 127;
  const int ty0 = (t >> 3) * 16;
  const int tx0 = (t & 7) * 32;
  const int tid = threadIdx.x, lane = tid & 63, wv = tid >> 6;
  const int quad = lane >> 4, l15 = lane & 15;
  constexpr int Kg = NCHUNK * 4;

  const ushort_t* s0n = s0 + (size_t)n * (65536 * 64);
  const ushort_t* s1n = s1 + (size_t)n * (65536 * 32);
  const ushort_t* s2n = s2 + (size_t)n * (65536 * 32);

  // staging geometry: element idx = tid + 256k -> pix = (tid>>2)+64k, cg = tid&3
  const int cg = tid & 3;
  int offs[10];
#pragma unroll
  for (int k = 0; k < 10; ++k) {
    const int pix = (tid >> 2) + 64 * k;
    int o = -1;
    if (pix < 612) {
      const int lr = pix / 34, lc = pix - lr * 34;
      const int gy = ty0 - 1 + lr, gx = tx0 - 1 + lc;
      if ((unsigned)gy < 256u && (unsigned)gx < 256u) o = gy * 256 + gx;
    }
    offs[k] = o;
  }

  const f32x4 zf = {0.f, 0.f, 0.f, 0.f};
  f32x4 acc[4][2][2];
#pragma unroll
  for (int r = 0; r < 4; ++r)
#pragma unroll
    for (int h = 0; h < 2; ++h) { acc[r][h][0] = zf; acc[r][h][1] = zf; }

#pragma unroll
  for (int ch = 0; ch < NCHUNK; ++ch) {
    const ushort_t* src; int cstr, cbase;
    if (ch < 2)       { src = s0n; cstr = 64; cbase = ch * 32; }
    else if (ch == 2) { src = s1n; cstr = 32; cbase = 0; }
    else              { src = s2n; cstr = 32; cbase = 0; }

    // batched global loads (independent -> one exposed latency, not ~10)
    s16x8 R[10];
#pragma unroll
    for (int k = 0; k < 10; ++k) {
      const int pix = (tid >> 2) + 64 * k;
      if (pix < 612) {
        s16x8 v = {0, 0, 0, 0, 0, 0, 0, 0};
        if (offs[k] >= 0)
          v = *(const s16x8*)(src + (size_t)offs[k] * cstr + cbase + cg * 8);
        R[k] = v;
      }
    }
    __syncthreads();
#pragma unroll
    for (int k = 0; k < 10; ++k) {
      const int pix = (tid >> 2) + 64 * k;
      if (pix < 612) *(s16x8*)&tile[pix * 40 + cg * 8] = R[k];
    }
    __syncthreads();

#pragma unroll
    for (int tap = 0; tap < 9; ++tap) {
      const int ky = tap / 3, kx = tap - ky * 3;
      const ushort_t* wb = wc + ((size_t)(tap * Kg + ch * 4 + quad) * 32 + l15) * 8;
      const s16x8 b0 = *(const s16x8*)wb;
      const s16x8 b1 = *(const s16x8*)(wb + 128);
#pragma unroll
      for (int r = 0; r < 4; ++r) {
        const int lr = 4 * wv + r + ky;
#pragma unroll
        for (int h = 0; h < 2; ++h) {
          const int lc = h * 16 + l15 + kx;
          const s16x8 a = *(const s16x8*)&tile[(lr * 34 + lc) * 40 + quad * 8];
          acc[r][h][0] = __builtin_amdgcn_mfma_f32_16x16x32_bf16(a, b0, acc[r][h][0], 0, 0, 0);
          acc[r][h][1] = __builtin_amdgcn_mfma_f32_16x16x32_bf16(a, b1, acc[r][h][1], 0, 0, 0);
        }
      }
    }
  }

  // ---- epilogue: acc -> LDS [512 px][stride 40] -> 8x b128 coalesced stores
  __syncthreads();   // all waves done reading tile
  const float bv0 = bias[l15], bv1 = bias[16 + l15];
#pragma unroll
  for (int r = 0; r < 4; ++r)
#pragma unroll
    for (int h = 0; h < 2; ++h)
#pragma unroll
      for (int i = 0; i < 4; ++i) {
        const int lpix = (4 * wv + r) * 32 + h * 16 + quad * 4 + i;
        tile[lpix * 40 + l15]      = f2bf(fmaxf(acc[r][h][0][i] + bv0, 0.f));
        tile[lpix * 40 + 16 + l15] = f2bf(fmaxf(acc[r][h][1][i] + bv1, 0.f));
      }
  __syncthreads();
  ushort_t* on = outp + (size_t)n * (65536 * 32);
#pragma unroll
  for (int k = 0; k < 8; ++k) {
    const int idx = tid + (k << 8);
    const int lpix = idx >> 2, cgg = idx & 3;
    const int gy = ty0 + (lpix >> 5), gx = tx0 + (lpix & 31);
    *(s16x8*)(on + (size_t)(gy * 256 + gx) * 32 + cgg * 8) =
        *(const s16x8*)&tile[lpix * 40 + cgg * 8];
  }
}

// ---------------------------------------------------------------------------
// fuse: out = cat(f0..f3)[160] x Wf^T + bf + x (unchanged).
// ---------------------------------------------------------------------------
__global__ __launch_bounds__(256) void fuse_kernel(
    const ushort_t* __restrict__ f0, const ushort_t* __restrict__ f1,
    const ushort_t* __restrict__ f2, const ushort_t* __restrict__ f3,
    const float* __restrict__ x, const ushort_t* __restrict__ wff,
    const float* __restrict__ bfv, float* __restrict__ out)
{
  __shared__ float tr[4][64 * 17];

  const int tid = threadIdx.x, lane = tid & 63, wv = tid >> 6;
  const int quad = lane >> 4, l15 = lane & 15;

  s16x8 wf[5][4];
#pragma unroll
  for (int ks = 0; ks < 5; ++ks)
#pragma unroll
    for (int nt = 0; nt < 4; ++nt)
      wf[ks][nt] = *(const s16x8*)(wff + ((size_t)((ks * 4 + quad) * 64) + nt * 16 + l15) * 8);
  float bb[4];
#pragma unroll
  for (int nt = 0; nt < 4; ++nt) bb[nt] = bfv[nt * 16 + l15];

  const int wt = blockIdx.x * 4 + wv;
  const f32x4 zf = {0.f, 0.f, 0.f, 0.f};
  float* trw = tr[wv];

  for (int mt = 0; mt < 4; ++mt) {
    const int p0 = wt * 64 + mt * 16;
    const size_t pA = (size_t)(p0 + l15);
    const s16x8 a0 = *(const s16x8*)(f0 + pA * 64 + quad * 8);
    const s16x8 a1 = *(const s16x8*)(f0 + pA * 64 + 32 + quad * 8);
    const s16x8 a2 = *(const s16x8*)(f1 + pA * 32 + quad * 8);
    const s16x8 a3 = *(const s16x8*)(f2 + pA * 32 + quad * 8);
    const s16x8 a4 = *(const s16x8*)(f3 + pA * 32 + quad * 8);

    f32x4 acc[4];
#pragma unroll
    for (int nt = 0; nt < 4; ++nt) {
      f32x4 d = zf;
      d = __builtin_amdgcn_mfma_f32_16x16x32_bf16(a0, wf[0][nt], d, 0, 0, 0);
      d = __builtin_amdgcn_mfma_f32_16x16x32_bf16(a1, wf[1][nt], d, 0, 0, 0);
      d = __builtin_amdgcn_mfma_f32_16x16x32_bf16(a2, wf[2][nt], d, 0, 0, 0);
      d = __builtin_amdgcn_mfma_f32_16x16x32_bf16(a3, wf[3][nt], d, 0, 0, 0);
      d = __builtin_amdgcn_mfma_f32_16x16x32_bf16(a4, wf[4][nt], d, 0, 0, 0);
      acc[nt] = d;
    }

#pragma unroll
    for (int nt = 0; nt < 4; ++nt)
#pragma unroll
      for (int i = 0; i < 4; ++i)
        trw[(nt * 16 + l15) * 17 + quad * 4 + i] = acc[nt][i] + bb[nt];

    const int n = p0 >> 16;
    const int pix0 = p0 & 65535;
    const float* xb = x + (size_t)n * (64 * 65536);
    float* ob = out + (size_t)n * (64 * 65536);
#pragma unroll
    for (int og = 0; og < 16; ++og) {
      const int o = og * 4 + quad;
      const float v = trw[o * 17 + l15];
      const size_t g = (size_t)o * 65536 + pix0 + l15;
      ob[g] = v + xb[g];
    }
  }
}

// ---------------------------------------------------------------------------
extern "C" void kernel_launch(void* const* d_in, const int* in_sizes, int n_in,
                              void* d_out, int out_size, void* d_ws, size_t ws_size,
                              hipStream_t stream)
{
  const float* x     = (const float*)d_in[0];
  const float* Wq    = (const float*)d_in[1];
  const float* bq    = (const float*)d_in[2];
  const float* Wk    = (const float*)d_in[3];
  const float* bk    = (const float*)d_in[4];
  const float* Wv    = (const float*)d_in[5];
  const float* bv    = (const float*)d_in[6];
  const float* Wo    = (const float*)d_in[7];
  const float* bo    = (const float*)d_in[8];
  const float* gamma = (const float*)d_in[9];
  const float* W1    = (const float*)d_in[10];
  const float* b1    = (const float*)d_in[11];
  const float* W2    = (const float*)d_in[12];
  const float* b2    = (const float*)d_in[13];
  const float* W3    = (const float*)d_in[14];
  const float* b3    = (const float*)d_in[15];
  const float* Wf    = (const float*)d_in[16];
  const float* bf    = (const float*)d_in[17];

  float* out = (float*)d_out;
  ushort_t* wsu = (ushort_t*)d_ws;

  // bf16 feature buffers, pixel-major [n][y][x][c]
  ushort_t* f0 = wsu;                       // 16,777,216
  ushort_t* f1 = wsu + 16777216;            //  8,388,608
  ushort_t* f2 = wsu + 25165824;            //  8,388,608
  ushort_t* f3 = wsu + 33554432;            //  8,388,608
  // xt overlays f1+f2 (dead before conv1 writes f1);
  // kg/vt overlay f3 (dead before conv3 writes f3)
  ushort_t* xtb = wsu + 16777216;           // 16,777,216
  ushort_t* kgb = wsu + 33554432;           //  2,097,152
  ushort_t* vtb = wsu + 35651584;           //  2,097,152
  ushort_t* wc1 = wsu + 41943040;           // 18432
  ushort_t* wc2 = wc1 + 18432;              // 27648
  ushort_t* wc3 = wc2 + 27648;              // 36864
  ushort_t* wff = wc3 + 36864;              // 10240
  ushort_t* woq = wff + 10240;              // 2048
  ushort_t* wou = woq + 2048;               // 2048

  repack_kernel<<<144, 256, 0, stream>>>(W1, W2, W3, Wf, Wq, Wo,
                                         wc1, wc2, wc3, wff, woq, wou);
  kvx_kernel<<<1024, 256, 0, stream>>>(x, Wk, bk, Wv, bv, xtb, kgb, vtb);
  attn_kernel<<<512, 512, 0, stream>>>(xtb, kgb, vtb, woq, bq, wou, bo, gamma, f0);
  conv3_kernel<2><<<512, 256, 0, stream>>>(f0, f1, f2, wc1, b1, f1);
  conv3_kernel<3><<<512, 256, 0, stream>>>(f0, f1, f2, wc2, b2, f2);
  conv3_kernel<4><<<512, 256, 0, stream>>>(f0, f1, f2, wc3, b3, f3);
  fuse_kernel<<<1024, 256, 0, stream>>>(f0, f1, f2, f3, x, wff, bf, out);
}